// Round 1
// baseline (701.204 us; speedup 1.0000x reference)
//
#include <hip/hip_runtime.h>
#include <cstdint>

typedef __bf16 bf16_t;
typedef __bf16 bf16x4 __attribute__((ext_vector_type(4)));
typedef __bf16 bf16x8 __attribute__((ext_vector_type(8)));
typedef float f32x4 __attribute__((ext_vector_type(4)));

#define B_ 4
#define S_ 1024
#define D_ 1024
#define HID_ 4096
#define MEG (1u << 20)

// ---------------- workspace layout (bytes) ----------------
// total ~184 MB; mlph (32MB bf16) aliases the scores (64MB f32) region
// (scores live only inside the attention loop, mlph only after it)
static const size_t OFF_WBF  = 0;                 // 12M bf16 = 25165824 (Wq,Wk,Wv,Wo,W1,W2)
static const size_t OFF_BQKV = 25165824;          // 3072 f32
static const size_t OFF_MOD  = 25178112;          // 4*6144 f32
static const size_t OFF_H    = 25276416;          // 4096*1024 bf16
static const size_t OFF_QKV  = 33665024;          // 4096*3072 bf16
static const size_t OFF_VT   = 58830848;          // 4*16*64*1024 bf16
static const size_t OFF_ATTN = 67219456;          // 4096*1024 bf16
static const size_t OFF_X1   = 75608064;          // 4096*1024 f32
static const size_t OFF_SC   = 92385280;          // 16*1024*1024 f32 (per-b scores) / mlph bf16
static const size_t OFF_PR   = 159494144;         // 16*1024*1024 bf16 (per-b probs)

// ---------------- async global->LDS (16B/lane) ----------------
__device__ __forceinline__ void async_copy16(const bf16_t* g, bf16_t* l) {
  __builtin_amdgcn_global_load_lds(
      (__attribute__((address_space(1))) void*)(g),
      (__attribute__((address_space(3))) void*)(l), 16, 0, 0);
}

// ---------------- weight convert + bias pack ----------------
__global__ __launch_bounds__(256) void convert_pack(
    const float* __restrict__ Wq, const float* __restrict__ Wk,
    const float* __restrict__ Wv, const float* __restrict__ Wo,
    const float* __restrict__ W1, const float* __restrict__ W2,
    const float* __restrict__ bq, const float* __restrict__ bk,
    const float* __restrict__ bv, bf16_t* __restrict__ wbf,
    float* __restrict__ bqkv) {
  const int y = blockIdx.y;
  if (y == 6) {
    int i = blockIdx.x * 256 + threadIdx.x;
    if (i < 3072)
      bqkv[i] = i < 1024 ? bq[i] : (i < 2048 ? bk[i - 1024] : bv[i - 2048]);
    return;
  }
  const float* src; bf16_t* dst; int n;
  switch (y) {
    case 0: src = Wq; dst = wbf;           n = MEG;     break;
    case 1: src = Wk; dst = wbf + MEG;     n = MEG;     break;
    case 2: src = Wv; dst = wbf + 2*MEG;   n = MEG;     break;
    case 3: src = Wo; dst = wbf + 3*MEG;   n = MEG;     break;
    case 4: src = W1; dst = wbf + 4*MEG;   n = 4*MEG;   break;
    default: src = W2; dst = wbf + 8*MEG;  n = 4*MEG;   break;
  }
  int idx = (blockIdx.x * 256 + threadIdx.x) * 4;
  if (idx < n) {
    float4 v = *(const float4*)(src + idx);
    bf16x4 pk;
    pk.x = (__bf16)v.x; pk.y = (__bf16)v.y; pk.z = (__bf16)v.z; pk.w = (__bf16)v.w;
    *(bf16x4*)(dst + idx) = pk;
  }
}

// ---------------- adaLN: mod[b,o] = silu(cond[b,:]) . Wada[o,:] + bada[o] ----------------
__global__ __launch_bounds__(256) void ada_mod(
    const float* __restrict__ cond, const float* __restrict__ Wada,
    const float* __restrict__ bada, float* __restrict__ mod) {
  const int wave = threadIdx.x >> 6, lane = threadIdx.x & 63;
  const int gw = blockIdx.x * 4 + wave;     // 0..24575
  const int b = gw / 6144, o = gw % 6144;
  const float* cb = cond + b * D_;
  const float* wr = Wada + (size_t)o * D_;
  float acc = 0.f;
#pragma unroll
  for (int l = 0; l < 16; l++) {
    int i = l * 64 + lane;
    float c = cb[i];
    float s = c / (1.0f + __expf(-c));
    acc += s * wr[i];
  }
#pragma unroll
  for (int offs = 32; offs; offs >>= 1) acc += __shfl_xor(acc, offs);
  if (lane == 0) mod[gw] = acc + bada[o];
}

// ---------------- LayerNorm + modulate -> bf16 ----------------
// h = ln(x) * (1 + beta[b,c]) + gama[b,c]; gama at mod[b, goff], beta at mod[b, goff+1024]
__global__ __launch_bounds__(256) void ln_modulate(
    const float* __restrict__ X, const float* __restrict__ mod,
    bf16_t* __restrict__ H, int goff) {
  const int row = blockIdx.x;
  const int b = row >> 10;
  const int t = threadIdx.x;
  const float* xr = X + (size_t)row * D_;
  float4 xv = *(const float4*)(xr + t * 4);
  float s = xv.x + xv.y + xv.z + xv.w;
  float q = xv.x*xv.x + xv.y*xv.y + xv.z*xv.z + xv.w*xv.w;
  const int wave = t >> 6, lane = t & 63;
#pragma unroll
  for (int offs = 32; offs; offs >>= 1) {
    s += __shfl_down(s, offs);
    q += __shfl_down(q, offs);
  }
  __shared__ float sb[4][2];
  if (lane == 0) { sb[wave][0] = s; sb[wave][1] = q; }
  __syncthreads();
  float st = sb[0][0] + sb[1][0] + sb[2][0] + sb[3][0];
  float qt = sb[0][1] + sb[1][1] + sb[2][1] + sb[3][1];
  float mu = st * (1.0f / D_);
  float var = qt * (1.0f / D_) - mu * mu;
  float rstd = rsqrtf(var + 1e-6f);
  const float* mb = mod + (size_t)b * 6144 + goff;
  const int c = t * 4;
  float4 gm = *(const float4*)(mb + c);
  float4 bt = *(const float4*)(mb + 1024 + c);
  bf16x4 pk;
  pk.x = (__bf16)((xv.x - mu) * rstd * (1.0f + bt.x) + gm.x);
  pk.y = (__bf16)((xv.y - mu) * rstd * (1.0f + bt.y) + gm.y);
  pk.z = (__bf16)((xv.z - mu) * rstd * (1.0f + bt.z) + gm.z);
  pk.w = (__bf16)((xv.w - mu) * rstd * (1.0f + bt.w) + gm.w);
  *(bf16x4*)(H + (size_t)row * D_ + c) = pk;
}

// ---------------- V transpose: vT[b,h,d,s] <- qkv[b,s, 2048+h*64+d] ----------------
__global__ __launch_bounds__(256) void transpose_v(
    const bf16_t* __restrict__ qkv, bf16_t* __restrict__ vT) {
  __shared__ bf16_t tile[64][65];
  const int bh = blockIdx.y;
  const int b = bh >> 4, hh = bh & 15;
  const int s0 = blockIdx.x * 64;
  const int t = threadIdx.x;
  const int tx = t & 63, ty = t >> 6;
  const bf16_t* src = qkv + (size_t)b * S_ * 3072 + 2048 + hh * 64;
  for (int r = ty; r < 64; r += 4)
    tile[r][tx] = src[(size_t)(s0 + r) * 3072 + tx];
  __syncthreads();
  bf16_t* dst = vT + (size_t)bh * 64 * 1024;
  for (int r = ty; r < 64; r += 4)
    dst[(size_t)r * 1024 + s0 + tx] = tile[tx][r];
}

// ---------------- softmax over rows of 1024 (f32 in, bf16 out) ----------------
__global__ __launch_bounds__(256) void softmax_rows(
    const float* __restrict__ S, bf16_t* __restrict__ P) {
  const int wave = threadIdx.x >> 6, lane = threadIdx.x & 63;
  const size_t row = (size_t)blockIdx.x * 4 + wave;
  const float* sr = S + row * 1024;
  float v[16];
  float m = -1e30f;
#pragma unroll
  for (int c = 0; c < 4; c++) {
    float4 x4 = *(const float4*)(sr + c * 256 + lane * 4);
    v[c*4+0] = x4.x; v[c*4+1] = x4.y; v[c*4+2] = x4.z; v[c*4+3] = x4.w;
    m = fmaxf(m, fmaxf(fmaxf(x4.x, x4.y), fmaxf(x4.z, x4.w)));
  }
#pragma unroll
  for (int offs = 32; offs; offs >>= 1) m = fmaxf(m, __shfl_xor(m, offs));
  float s = 0.f;
#pragma unroll
  for (int i = 0; i < 16; i++) { v[i] = __expf(v[i] - m); s += v[i]; }
#pragma unroll
  for (int offs = 32; offs; offs >>= 1) s += __shfl_xor(s, offs);
  float inv = 1.0f / s;
  bf16_t* pr = P + row * 1024;
#pragma unroll
  for (int c = 0; c < 4; c++) {
    bf16x4 pk;
    pk.x = (__bf16)(v[c*4+0] * inv); pk.y = (__bf16)(v[c*4+1] * inv);
    pk.z = (__bf16)(v[c*4+2] * inv); pk.w = (__bf16)(v[c*4+3] * inv);
    *(bf16x4*)(pr + c * 256 + lane * 4) = pk;
  }
}

// ---------------- generic C = A * B^T GEMM (bf16 in, f32 acc) ----------------
// EPI: 0 = (+bias) -> bf16 store
//      1 = *scale -> f32 store
//      2 = resid + alpha[b,col]*(acc+bias) -> f32 store   (b = row>>10)
//      3 = gelu_erf(acc+bias) -> bf16 store
template <int EPI>
__global__ __launch_bounds__(256) void gemm_bt(
    const bf16_t* __restrict__ A, int lda, long long sAz,
    const bf16_t* __restrict__ B, int ldb, long long sBz,
    void* __restrict__ Cv, int ldc, long long sCz,
    int M, int N, int K,
    const float* __restrict__ bias,
    const float* __restrict__ resid,
    const float* __restrict__ alpha,
    float scale) {
  __shared__ __align__(16) bf16_t As[128 * 32];
  __shared__ __align__(16) bf16_t Bs[128 * 32];

  const int z = blockIdx.z;
  A += (size_t)z * sAz;
  B += (size_t)z * sBz;

  const int t = threadIdx.x;
  const int wave = t >> 6;
  const int lane = t & 63;
  const int lm = lane & 15;
  const int quad = lane >> 4;
  const int wr = wave >> 1;
  const int wc = wave & 1;

  const int m0 = blockIdx.y * 128;
  const int n0 = blockIdx.x * 128;

  f32x4 acc[4][4] = {};

  const int srow = t >> 2;          // 0..63
  const int scol = (t & 3) * 8;     // 0,8,16,24

  for (int k0 = 0; k0 < K; k0 += 32) {
    __syncthreads();
    {
      int gr0 = m0 + srow;       if (gr0 > M - 1) gr0 = M - 1;
      int gr1 = m0 + srow + 64;  if (gr1 > M - 1) gr1 = M - 1;
      async_copy16(A + (size_t)gr0 * lda + k0 + scol, &As[srow * 32 + scol]);
      async_copy16(A + (size_t)gr1 * lda + k0 + scol, &As[(srow + 64) * 32 + scol]);
      int gn0 = n0 + srow;       if (gn0 > N - 1) gn0 = N - 1;
      int gn1 = n0 + srow + 64;  if (gn1 > N - 1) gn1 = N - 1;
      async_copy16(B + (size_t)gn0 * ldb + k0 + scol, &Bs[srow * 32 + scol]);
      async_copy16(B + (size_t)gn1 * ldb + k0 + scol, &Bs[(srow + 64) * 32 + scol]);
    }
    __syncthreads();

    bf16x8 af[4], bfr[4];
#pragma unroll
    for (int i = 0; i < 4; i++)
      af[i] = *(const bf16x8*)&As[(wr * 64 + i * 16 + lm) * 32 + quad * 8];
#pragma unroll
    for (int i = 0; i < 4; i++)
      bfr[i] = *(const bf16x8*)&Bs[(wc * 64 + i * 16 + lm) * 32 + quad * 8];
#pragma unroll
    for (int mi = 0; mi < 4; mi++)
#pragma unroll
      for (int ni = 0; ni < 4; ni++)
        acc[mi][ni] = __builtin_amdgcn_mfma_f32_16x16x32_bf16(
            af[mi], bfr[ni], acc[mi][ni], 0, 0, 0);
  }

  const size_t cz = (size_t)z * sCz;
#pragma unroll
  for (int mi = 0; mi < 4; mi++) {
#pragma unroll
    for (int ni = 0; ni < 4; ni++) {
#pragma unroll
      for (int r = 0; r < 4; r++) {
        int row = m0 + wr * 64 + mi * 16 + quad * 4 + r;
        int col = n0 + wc * 64 + ni * 16 + lm;
        if (row < M && col < N) {
          float v = acc[mi][ni][r];
          size_t idx = cz + (size_t)row * ldc + col;
          if (EPI == 1) {
            ((float*)Cv)[idx] = v * scale;
          } else if (EPI == 0) {
            if (bias) v += bias[col];
            ((bf16_t*)Cv)[idx] = (__bf16)v;
          } else if (EPI == 3) {
            v += bias[col];
            float g = 0.5f * v * (1.0f + erff(v * 0.70710678118654752f));
            ((bf16_t*)Cv)[idx] = (__bf16)g;
          } else {  // EPI == 2
            v += bias[col];
            int bb = row >> 10;
            float a = alpha[(size_t)bb * 6144 + col];
            ((float*)Cv)[idx] = resid[(size_t)row * ldc + col] + a * v;
          }
        }
      }
    }
  }
}

extern "C" void kernel_launch(void* const* d_in, const int* in_sizes, int n_in,
                              void* d_out, int out_size, void* d_ws, size_t ws_size,
                              hipStream_t stream) {
  (void)in_sizes; (void)n_in; (void)out_size; (void)ws_size;
  const float* x    = (const float*)d_in[0];
  const float* cond = (const float*)d_in[1];
  const float* Wq   = (const float*)d_in[2];
  const float* bq   = (const float*)d_in[3];
  const float* Wk   = (const float*)d_in[4];
  const float* bk   = (const float*)d_in[5];
  const float* Wv   = (const float*)d_in[6];
  const float* bv   = (const float*)d_in[7];
  const float* Wo   = (const float*)d_in[8];
  const float* bo   = (const float*)d_in[9];
  const float* W1   = (const float*)d_in[10];
  const float* b1   = (const float*)d_in[11];
  const float* W2   = (const float*)d_in[12];
  const float* b2   = (const float*)d_in[13];
  const float* Wada = (const float*)d_in[14];
  const float* bada = (const float*)d_in[15];

  uint8_t* ws = (uint8_t*)d_ws;
  bf16_t* wbf   = (bf16_t*)(ws + OFF_WBF);
  float*  bqkv  = (float*)(ws + OFF_BQKV);
  float*  mod   = (float*)(ws + OFF_MOD);
  bf16_t* h     = (bf16_t*)(ws + OFF_H);
  bf16_t* qkv   = (bf16_t*)(ws + OFF_QKV);
  bf16_t* vT    = (bf16_t*)(ws + OFF_VT);
  bf16_t* attn  = (bf16_t*)(ws + OFF_ATTN);
  float*  x1    = (float*)(ws + OFF_X1);
  float*  scores= (float*)(ws + OFF_SC);
  bf16_t* mlph  = (bf16_t*)(ws + OFF_SC);   // aliases scores (disjoint lifetime)
  bf16_t* probs = (bf16_t*)(ws + OFF_PR);
  float* out = (float*)d_out;

  // weights -> bf16, pack qkv bias
  convert_pack<<<dim3(4096, 7, 1), 256, 0, stream>>>(Wq, Wk, Wv, Wo, W1, W2,
                                                     bq, bk, bv, wbf, bqkv);
  // adaLN modulation vector
  ada_mod<<<6144, 256, 0, stream>>>(cond, Wada, bada, mod);
  // h = modulate(ln(x), beta1, gama1)
  ln_modulate<<<4096, 256, 0, stream>>>(x, mod, h, 0);
  // qkv = h @ [Wq;Wk;Wv]^T + bias  (bf16 out)
  gemm_bt<0><<<dim3(24, 32, 1), 256, 0, stream>>>(
      h, 1024, 0, wbf, 1024, 0, qkv, 3072, 0, 4096, 3072, 1024,
      bqkv, nullptr, nullptr, 1.f);
  transpose_v<<<dim3(16, 64, 1), 256, 0, stream>>>(qkv, vT);

  for (int b = 0; b < B_; b++) {
    const bf16_t* qb = qkv + (size_t)b * S_ * 3072;
    // scores[h,q,k] = (Q K^T)/8
    gemm_bt<1><<<dim3(8, 8, 16), 256, 0, stream>>>(
        qb, 3072, 64, qb + 1024, 3072, 64, scores, 1024, 1048576,
        1024, 1024, 64, nullptr, nullptr, nullptr, 0.125f);
    softmax_rows<<<4096, 256, 0, stream>>>(scores, probs);
    // attn[b, q, h*64+d] = P @ V
    gemm_bt<0><<<dim3(1, 8, 16), 256, 0, stream>>>(
        probs, 1024, 1048576, vT + (size_t)b * 16 * 64 * 1024, 1024, 65536,
        attn + (size_t)b * S_ * 1024, 1024, 64,
        1024, 64, 1024, nullptr, nullptr, nullptr, 1.f);
  }

  // x1 = x + alpha1 * (attn @ Wo^T + bo)
  gemm_bt<2><<<dim3(8, 32, 1), 256, 0, stream>>>(
      attn, 1024, 0, wbf + (size_t)3 * MEG, 1024, 0, x1, 1024, 0,
      4096, 1024, 1024, bo, x, mod + 2048, 1.f);
  // h = modulate(ln(x1), beta2, gama2)
  ln_modulate<<<4096, 256, 0, stream>>>(x1, mod, h, 3072);
  // mlph = gelu(h @ W1^T + b1)
  gemm_bt<3><<<dim3(32, 32, 1), 256, 0, stream>>>(
      h, 1024, 0, wbf + (size_t)4 * MEG, 1024, 0, mlph, 4096, 0,
      4096, 4096, 1024, b1, nullptr, nullptr, 1.f);
  // out = x1 + alpha2 * (mlph @ W2^T + b2)
  gemm_bt<2><<<dim3(8, 32, 1), 256, 0, stream>>>(
      mlph, 4096, 0, wbf + (size_t)8 * MEG, 4096, 0, out, 1024, 0,
      4096, 1024, 4096, b2, x1, mod + 5120, 1.f);
}

// Round 2
// 652.853 us; speedup vs baseline: 1.0741x; 1.0741x over previous
//
#include <hip/hip_runtime.h>
#include <cstdint>

typedef __bf16 bf16_t;
typedef __bf16 bf16x4 __attribute__((ext_vector_type(4)));
typedef __bf16 bf16x8 __attribute__((ext_vector_type(8)));
typedef float f32x4 __attribute__((ext_vector_type(4)));

#define B_ 4
#define S_ 1024
#define D_ 1024
#define HID_ 4096
#define MEG (1u << 20)

// ---------------- workspace layout (bytes) ----------------
static const size_t OFF_WBF  = 0;                 // 12M bf16 (Wq,Wk,Wv,Wo,W1,W2)
static const size_t OFF_BQKV = 25165824;          // 3072 f32
static const size_t OFF_MOD  = 25178112;          // 4*6144 f32
static const size_t OFF_H    = 25276416;          // 4096*1024 bf16
static const size_t OFF_QKV  = 33665024;          // 4096*3072 bf16
static const size_t OFF_VT   = 58830848;          // 4*16*64*1024 bf16
static const size_t OFF_ATTN = 67219456;          // 4096*1024 bf16
static const size_t OFF_X1   = 75608064;          // 4096*1024 f32
static const size_t OFF_SC   = 92385280;          // 16*1024*1024 f32 (per-b scores) / mlph bf16
static const size_t OFF_PR   = 159494144;         // 16*1024*1024 bf16 (per-b probs)

// ---------------- async global->LDS (16B/lane) ----------------
__device__ __forceinline__ void async_copy16(const bf16_t* g, bf16_t* l) {
  __builtin_amdgcn_global_load_lds(
      (__attribute__((address_space(1))) void*)(g),
      (__attribute__((address_space(3))) void*)(l), 16, 0, 0);
}

// ---------------- weight convert + bias pack ----------------
__global__ __launch_bounds__(256) void convert_pack(
    const float* __restrict__ Wq, const float* __restrict__ Wk,
    const float* __restrict__ Wv, const float* __restrict__ Wo,
    const float* __restrict__ W1, const float* __restrict__ W2,
    const float* __restrict__ bq, const float* __restrict__ bk,
    const float* __restrict__ bv, bf16_t* __restrict__ wbf,
    float* __restrict__ bqkv) {
  const int y = blockIdx.y;
  if (y == 6) {
    int i = blockIdx.x * 256 + threadIdx.x;
    if (i < 3072)
      bqkv[i] = i < 1024 ? bq[i] : (i < 2048 ? bk[i - 1024] : bv[i - 2048]);
    return;
  }
  const float* src; bf16_t* dst; int n;
  switch (y) {
    case 0: src = Wq; dst = wbf;           n = MEG;     break;
    case 1: src = Wk; dst = wbf + MEG;     n = MEG;     break;
    case 2: src = Wv; dst = wbf + 2*MEG;   n = MEG;     break;
    case 3: src = Wo; dst = wbf + 3*MEG;   n = MEG;     break;
    case 4: src = W1; dst = wbf + 4*MEG;   n = 4*MEG;   break;
    default: src = W2; dst = wbf + 8*MEG;  n = 4*MEG;   break;
  }
  int idx = (blockIdx.x * 256 + threadIdx.x) * 4;
  if (idx < n) {
    float4 v = *(const float4*)(src + idx);
    bf16x4 pk;
    pk.x = (__bf16)v.x; pk.y = (__bf16)v.y; pk.z = (__bf16)v.z; pk.w = (__bf16)v.w;
    *(bf16x4*)(dst + idx) = pk;
  }
}

// ---------------- adaLN: mod[b,o] = silu(cond[b,:]) . Wada[o,:] + bada[o] ----------------
__global__ __launch_bounds__(256) void ada_mod(
    const float* __restrict__ cond, const float* __restrict__ Wada,
    const float* __restrict__ bada, float* __restrict__ mod) {
  const int wave = threadIdx.x >> 6, lane = threadIdx.x & 63;
  const int gw = blockIdx.x * 4 + wave;     // 0..24575
  const int b = gw / 6144, o = gw % 6144;
  const float* cb = cond + b * D_;
  const float* wr = Wada + (size_t)o * D_;
  float acc = 0.f;
#pragma unroll
  for (int l = 0; l < 16; l++) {
    int i = l * 64 + lane;
    float c = cb[i];
    float s = c / (1.0f + __expf(-c));
    acc += s * wr[i];
  }
#pragma unroll
  for (int offs = 32; offs; offs >>= 1) acc += __shfl_xor(acc, offs);
  if (lane == 0) mod[gw] = acc + bada[o];
}

// ---------------- LayerNorm + modulate -> bf16 ----------------
__global__ __launch_bounds__(256) void ln_modulate(
    const float* __restrict__ X, const float* __restrict__ mod,
    bf16_t* __restrict__ H, int goff) {
  const int row = blockIdx.x;
  const int b = row >> 10;
  const int t = threadIdx.x;
  const float* xr = X + (size_t)row * D_;
  float4 xv = *(const float4*)(xr + t * 4);
  float s = xv.x + xv.y + xv.z + xv.w;
  float q = xv.x*xv.x + xv.y*xv.y + xv.z*xv.z + xv.w*xv.w;
  const int wave = t >> 6, lane = t & 63;
#pragma unroll
  for (int offs = 32; offs; offs >>= 1) {
    s += __shfl_down(s, offs);
    q += __shfl_down(q, offs);
  }
  __shared__ float sb[4][2];
  if (lane == 0) { sb[wave][0] = s; sb[wave][1] = q; }
  __syncthreads();
  float st = sb[0][0] + sb[1][0] + sb[2][0] + sb[3][0];
  float qt = sb[0][1] + sb[1][1] + sb[2][1] + sb[3][1];
  float mu = st * (1.0f / D_);
  float var = qt * (1.0f / D_) - mu * mu;
  float rstd = rsqrtf(var + 1e-6f);
  const float* mb = mod + (size_t)b * 6144 + goff;
  const int c = t * 4;
  float4 gm = *(const float4*)(mb + c);
  float4 bt = *(const float4*)(mb + 1024 + c);
  bf16x4 pk;
  pk.x = (__bf16)((xv.x - mu) * rstd * (1.0f + bt.x) + gm.x);
  pk.y = (__bf16)((xv.y - mu) * rstd * (1.0f + bt.y) + gm.y);
  pk.z = (__bf16)((xv.z - mu) * rstd * (1.0f + bt.z) + gm.z);
  pk.w = (__bf16)((xv.w - mu) * rstd * (1.0f + bt.w) + gm.w);
  *(bf16x4*)(H + (size_t)row * D_ + c) = pk;
}

// ---------------- V transpose: vT[b,h,d,s] <- qkv[b,s, 2048+h*64+d] ----------------
__global__ __launch_bounds__(256) void transpose_v(
    const bf16_t* __restrict__ qkv, bf16_t* __restrict__ vT) {
  __shared__ bf16_t tile[64][65];
  const int bh = blockIdx.y;
  const int b = bh >> 4, hh = bh & 15;
  const int s0 = blockIdx.x * 64;
  const int t = threadIdx.x;
  const int tx = t & 63, ty = t >> 6;
  const bf16_t* src = qkv + (size_t)b * S_ * 3072 + 2048 + hh * 64;
  for (int r = ty; r < 64; r += 4)
    tile[r][tx] = src[(size_t)(s0 + r) * 3072 + tx];
  __syncthreads();
  bf16_t* dst = vT + (size_t)bh * 64 * 1024;
  for (int r = ty; r < 64; r += 4)
    dst[(size_t)r * 1024 + s0 + tx] = tile[tx][r];
}

// ---------------- softmax over rows of 1024 (f32 in, bf16 out) ----------------
__global__ __launch_bounds__(256) void softmax_rows(
    const float* __restrict__ S, bf16_t* __restrict__ P) {
  const int wave = threadIdx.x >> 6, lane = threadIdx.x & 63;
  const size_t row = (size_t)blockIdx.x * 4 + wave;
  const float* sr = S + row * 1024;
  float v[16];
  float m = -1e30f;
#pragma unroll
  for (int c = 0; c < 4; c++) {
    float4 x4 = *(const float4*)(sr + c * 256 + lane * 4);
    v[c*4+0] = x4.x; v[c*4+1] = x4.y; v[c*4+2] = x4.z; v[c*4+3] = x4.w;
    m = fmaxf(m, fmaxf(fmaxf(x4.x, x4.y), fmaxf(x4.z, x4.w)));
  }
#pragma unroll
  for (int offs = 32; offs; offs >>= 1) m = fmaxf(m, __shfl_xor(m, offs));
  float s = 0.f;
#pragma unroll
  for (int i = 0; i < 16; i++) { v[i] = __expf(v[i] - m); s += v[i]; }
#pragma unroll
  for (int offs = 32; offs; offs >>= 1) s += __shfl_xor(s, offs);
  float inv = 1.0f / s;
  bf16_t* pr = P + row * 1024;
#pragma unroll
  for (int c = 0; c < 4; c++) {
    bf16x4 pk;
    pk.x = (__bf16)(v[c*4+0] * inv); pk.y = (__bf16)(v[c*4+1] * inv);
    pk.z = (__bf16)(v[c*4+2] * inv); pk.w = (__bf16)(v[c*4+3] * inv);
    *(bf16x4*)(pr + c * 256 + lane * 4) = pk;
  }
}

// ---------------- generic C = A * B^T GEMM (bf16 in, f32 acc) ----------------
// BK=64, XOR-swizzled LDS: LDS slot (row, c^) holds global 8-elem chunk (c^ ^ (row&7)).
// EPI: 0 = (+bias) -> bf16 store
//      1 = *scale -> f32 store
//      2 = resid + alpha[b,col]*(acc+bias) -> f32 store   (b = row>>10)
//      3 = gelu_erf(acc+bias) -> bf16 store
template <int EPI>
__global__ __launch_bounds__(256) void gemm_bt(
    const bf16_t* __restrict__ A, int lda, long long sAz,
    const bf16_t* __restrict__ B, int ldb, long long sBz,
    void* __restrict__ Cv, int ldc, long long sCz,
    int M, int N, int K,
    const float* __restrict__ bias,
    const float* __restrict__ resid,
    const float* __restrict__ alpha,
    float scale) {
  __shared__ __align__(16) bf16_t As[128 * 64];
  __shared__ __align__(16) bf16_t Bs[128 * 64];

  const int z = blockIdx.z;
  A += (size_t)z * sAz;
  B += (size_t)z * sBz;

  const int t = threadIdx.x;
  const int wave = t >> 6;
  const int lane = t & 63;
  const int lm = lane & 15;
  const int quad = lane >> 4;
  const int wr = wave >> 1;
  const int wc = wave & 1;

  const int m0 = blockIdx.y * 128;
  const int n0 = blockIdx.x * 128;

  f32x4 acc[4][4] = {};

  // staging: wave w covers LDS rows [w*32, w*32+32), 4 instrs of 8 rows each.
  // per-lane LDS element offset = wave*2048 + j*512 + lane*8 (lane-linear, required).
  // LDS row (local) = wave*32 + j*8 + (lane>>3); slot chunk c^ = lane&7.
  // global chunk = c^ ^ (row&7); row&7 == lane>>3 here.
  const int srow = (lane >> 3);               // row-within-8-group
  const int gchunk = (lane & 7) ^ srow;       // global chunk index (0..7)
  const int goff = gchunk * 8;                // global col offset within k-tile
  const int lds_lin = wave * 2048 + lane * 8; // + j*512

  for (int k0 = 0; k0 < K; k0 += 64) {
    __syncthreads();
#pragma unroll
    for (int j = 0; j < 4; j++) {
      int row = wave * 32 + j * 8 + srow;
      int ga = m0 + row; if (ga > M - 1) ga = M - 1;
      int gb = n0 + row; if (gb > N - 1) gb = N - 1;
      async_copy16(A + (size_t)ga * lda + k0 + goff, &As[lds_lin + j * 512]);
      async_copy16(B + (size_t)gb * ldb + k0 + goff, &Bs[lds_lin + j * 512]);
    }
    __syncthreads();

#pragma unroll
    for (int ks = 0; ks < 2; ks++) {
      bf16x8 af[4], bfr[4];
#pragma unroll
      for (int i = 0; i < 4; i++) {
        int ra = wr * 64 + i * 16 + lm;
        int ca = (ks * 4 + quad) ^ (ra & 7);
        af[i] = *(const bf16x8*)&As[ra * 64 + ca * 8];
        int rb = wc * 64 + i * 16 + lm;
        int cb = (ks * 4 + quad) ^ (rb & 7);
        bfr[i] = *(const bf16x8*)&Bs[rb * 64 + cb * 8];
      }
#pragma unroll
      for (int mi = 0; mi < 4; mi++)
#pragma unroll
        for (int ni = 0; ni < 4; ni++)
          acc[mi][ni] = __builtin_amdgcn_mfma_f32_16x16x32_bf16(
              af[mi], bfr[ni], acc[mi][ni], 0, 0, 0);
    }
  }

  const size_t cz = (size_t)z * sCz;
#pragma unroll
  for (int mi = 0; mi < 4; mi++) {
#pragma unroll
    for (int ni = 0; ni < 4; ni++) {
#pragma unroll
      for (int r = 0; r < 4; r++) {
        int row = m0 + wr * 64 + mi * 16 + quad * 4 + r;
        int col = n0 + wc * 64 + ni * 16 + lm;
        if (row < M && col < N) {
          float v = acc[mi][ni][r];
          size_t idx = cz + (size_t)row * ldc + col;
          if (EPI == 1) {
            ((float*)Cv)[idx] = v * scale;
          } else if (EPI == 0) {
            if (bias) v += bias[col];
            ((bf16_t*)Cv)[idx] = (__bf16)v;
          } else if (EPI == 3) {
            v += bias[col];
            float g = 0.5f * v * (1.0f + erff(v * 0.70710678118654752f));
            ((bf16_t*)Cv)[idx] = (__bf16)g;
          } else {  // EPI == 2
            v += bias[col];
            int bb = row >> 10;
            float a = alpha[(size_t)bb * 6144 + col];
            ((float*)Cv)[idx] = resid[(size_t)row * ldc + col] + a * v;
          }
        }
      }
    }
  }
}

extern "C" void kernel_launch(void* const* d_in, const int* in_sizes, int n_in,
                              void* d_out, int out_size, void* d_ws, size_t ws_size,
                              hipStream_t stream) {
  (void)in_sizes; (void)n_in; (void)out_size; (void)ws_size;
  const float* x    = (const float*)d_in[0];
  const float* cond = (const float*)d_in[1];
  const float* Wq   = (const float*)d_in[2];
  const float* bq   = (const float*)d_in[3];
  const float* Wk   = (const float*)d_in[4];
  const float* bk   = (const float*)d_in[5];
  const float* Wv   = (const float*)d_in[6];
  const float* bv   = (const float*)d_in[7];
  const float* Wo   = (const float*)d_in[8];
  const float* bo   = (const float*)d_in[9];
  const float* W1   = (const float*)d_in[10];
  const float* b1   = (const float*)d_in[11];
  const float* W2   = (const float*)d_in[12];
  const float* b2   = (const float*)d_in[13];
  const float* Wada = (const float*)d_in[14];
  const float* bada = (const float*)d_in[15];

  uint8_t* ws = (uint8_t*)d_ws;
  bf16_t* wbf   = (bf16_t*)(ws + OFF_WBF);
  float*  bqkv  = (float*)(ws + OFF_BQKV);
  float*  mod   = (float*)(ws + OFF_MOD);
  bf16_t* h     = (bf16_t*)(ws + OFF_H);
  bf16_t* qkv   = (bf16_t*)(ws + OFF_QKV);
  bf16_t* vT    = (bf16_t*)(ws + OFF_VT);
  bf16_t* attn  = (bf16_t*)(ws + OFF_ATTN);
  float*  x1    = (float*)(ws + OFF_X1);
  float*  scores= (float*)(ws + OFF_SC);
  bf16_t* mlph  = (bf16_t*)(ws + OFF_SC);   // aliases scores (disjoint lifetime)
  bf16_t* probs = (bf16_t*)(ws + OFF_PR);
  float* out = (float*)d_out;

  // weights -> bf16, pack qkv bias
  convert_pack<<<dim3(4096, 7, 1), 256, 0, stream>>>(Wq, Wk, Wv, Wo, W1, W2,
                                                     bq, bk, bv, wbf, bqkv);
  // adaLN modulation vector
  ada_mod<<<6144, 256, 0, stream>>>(cond, Wada, bada, mod);
  // h = modulate(ln(x), beta1, gama1)
  ln_modulate<<<4096, 256, 0, stream>>>(x, mod, h, 0);
  // qkv = h @ [Wq;Wk;Wv]^T + bias  (bf16 out)
  gemm_bt<0><<<dim3(24, 32, 1), 256, 0, stream>>>(
      h, 1024, 0, wbf, 1024, 0, qkv, 3072, 0, 4096, 3072, 1024,
      bqkv, nullptr, nullptr, 1.f);
  transpose_v<<<dim3(16, 64, 1), 256, 0, stream>>>(qkv, vT);

  for (int b = 0; b < B_; b++) {
    const bf16_t* qb = qkv + (size_t)b * S_ * 3072;
    // scores[h,q,k] = (Q K^T)/8
    gemm_bt<1><<<dim3(8, 8, 16), 256, 0, stream>>>(
        qb, 3072, 64, qb + 1024, 3072, 64, scores, 1024, 1048576,
        1024, 1024, 64, nullptr, nullptr, nullptr, 0.125f);
    softmax_rows<<<4096, 256, 0, stream>>>(scores, probs);
    // attn[b, q, h*64+d] = P @ V
    gemm_bt<0><<<dim3(1, 8, 16), 256, 0, stream>>>(
        probs, 1024, 1048576, vT + (size_t)b * 16 * 64 * 1024, 1024, 65536,
        attn + (size_t)b * S_ * 1024, 1024, 64,
        1024, 64, 1024, nullptr, nullptr, nullptr, 1.f);
  }

  // x1 = x + alpha1 * (attn @ Wo^T + bo)
  gemm_bt<2><<<dim3(8, 32, 1), 256, 0, stream>>>(
      attn, 1024, 0, wbf + (size_t)3 * MEG, 1024, 0, x1, 1024, 0,
      4096, 1024, 1024, bo, x, mod + 2048, 1.f);
  // h = modulate(ln(x1), beta2, gama2)
  ln_modulate<<<4096, 256, 0, stream>>>(x1, mod, h, 3072);
  // mlph = gelu(h @ W1^T + b1)
  gemm_bt<3><<<dim3(32, 32, 1), 256, 0, stream>>>(
      h, 1024, 0, wbf + (size_t)4 * MEG, 1024, 0, mlph, 4096, 0,
      4096, 4096, 1024, b1, nullptr, nullptr, 1.f);
  // out = x1 + alpha2 * (mlph @ W2^T + b2)
  gemm_bt<2><<<dim3(8, 32, 1), 256, 0, stream>>>(
      mlph, 4096, 0, wbf + (size_t)8 * MEG, 4096, 0, out, 1024, 0,
      4096, 1024, 4096, b2, x1, mod + 5120, 1.f);
}

// Round 3
// 478.153 us; speedup vs baseline: 1.4665x; 1.3654x over previous
//
#include <hip/hip_runtime.h>
#include <cstdint>

typedef __bf16 bf16_t;
typedef __bf16 bf16x4 __attribute__((ext_vector_type(4)));
typedef __bf16 bf16x8 __attribute__((ext_vector_type(8)));
typedef float f32x4 __attribute__((ext_vector_type(4)));

#define B_ 4
#define S_ 1024
#define D_ 1024
#define HID_ 4096
#define MEG (1u << 20)

// ---------------- workspace layout (bytes) ----------------
static const size_t OFF_WBF  = 0;                 // 12M bf16 (Wq,Wk,Wv,Wo,W1,W2)
static const size_t OFF_BQKV = 25165824;          // 3072 f32
static const size_t OFF_MOD  = 25178112;          // 4*6144 f32
static const size_t OFF_H    = 25276416;          // 4096*1024 bf16
static const size_t OFF_QKV  = 33665024;          // 4096*3072 bf16
static const size_t OFF_VT   = 58830848;          // 4*16*64*1024 bf16
static const size_t OFF_ATTN = 67219456;          // 4096*1024 bf16
static const size_t OFF_X1   = 75608064;          // 4096*1024 f32
static const size_t OFF_PART = 92385280;          // 4 * 4096*1024 f32 = 64MB (W2 split-K partials)
static const size_t OFF_MLPH = 159494144;         // 4096*4096 bf16 = 32MB

// ---------------- async global->LDS (16B/lane) ----------------
__device__ __forceinline__ void async_copy16(const bf16_t* g, bf16_t* l) {
  __builtin_amdgcn_global_load_lds(
      (__attribute__((address_space(1))) void*)(g),
      (__attribute__((address_space(3))) void*)(l), 16, 0, 0);
}

// ---------------- weight convert + bias pack ----------------
__global__ __launch_bounds__(256) void convert_pack(
    const float* __restrict__ Wq, const float* __restrict__ Wk,
    const float* __restrict__ Wv, const float* __restrict__ Wo,
    const float* __restrict__ W1, const float* __restrict__ W2,
    const float* __restrict__ bq, const float* __restrict__ bk,
    const float* __restrict__ bv, bf16_t* __restrict__ wbf,
    float* __restrict__ bqkv) {
  const int y = blockIdx.y;
  if (y == 6) {
    int i = blockIdx.x * 256 + threadIdx.x;
    if (i < 3072)
      bqkv[i] = i < 1024 ? bq[i] : (i < 2048 ? bk[i - 1024] : bv[i - 2048]);
    return;
  }
  const float* src; bf16_t* dst; int n;
  switch (y) {
    case 0: src = Wq; dst = wbf;           n = MEG;     break;
    case 1: src = Wk; dst = wbf + MEG;     n = MEG;     break;
    case 2: src = Wv; dst = wbf + 2*MEG;   n = MEG;     break;
    case 3: src = Wo; dst = wbf + 3*MEG;   n = MEG;     break;
    case 4: src = W1; dst = wbf + 4*MEG;   n = 4*MEG;   break;
    default: src = W2; dst = wbf + 8*MEG;  n = 4*MEG;   break;
  }
  int idx = (blockIdx.x * 256 + threadIdx.x) * 4;
  if (idx < n) {
    float4 v = *(const float4*)(src + idx);
    bf16x4 pk;
    pk.x = (__bf16)v.x; pk.y = (__bf16)v.y; pk.z = (__bf16)v.z; pk.w = (__bf16)v.w;
    *(bf16x4*)(dst + idx) = pk;
  }
}

// ---------------- adaLN: mod[b,o] = silu(cond[b,:]) . Wada[o,:] + bada[o] ----------------
__global__ __launch_bounds__(256) void ada_mod(
    const float* __restrict__ cond, const float* __restrict__ Wada,
    const float* __restrict__ bada, float* __restrict__ mod) {
  const int wave = threadIdx.x >> 6, lane = threadIdx.x & 63;
  const int gw = blockIdx.x * 4 + wave;     // 0..24575
  const int b = gw / 6144, o = gw % 6144;
  const float* cb = cond + b * D_;
  const float* wr = Wada + (size_t)o * D_;
  float acc = 0.f;
#pragma unroll
  for (int l = 0; l < 16; l++) {
    int i = l * 64 + lane;
    float c = cb[i];
    float s = c / (1.0f + __expf(-c));
    acc += s * wr[i];
  }
#pragma unroll
  for (int offs = 32; offs; offs >>= 1) acc += __shfl_xor(acc, offs);
  if (lane == 0) mod[gw] = acc + bada[o];
}

// ---------------- LayerNorm + modulate -> bf16 ----------------
__global__ __launch_bounds__(256) void ln_modulate(
    const float* __restrict__ X, const float* __restrict__ mod,
    bf16_t* __restrict__ H, int goff) {
  const int row = blockIdx.x;
  const int b = row >> 10;
  const int t = threadIdx.x;
  const float* xr = X + (size_t)row * D_;
  float4 xv = *(const float4*)(xr + t * 4);
  float s = xv.x + xv.y + xv.z + xv.w;
  float q = xv.x*xv.x + xv.y*xv.y + xv.z*xv.z + xv.w*xv.w;
  const int wave = t >> 6, lane = t & 63;
#pragma unroll
  for (int offs = 32; offs; offs >>= 1) {
    s += __shfl_down(s, offs);
    q += __shfl_down(q, offs);
  }
  __shared__ float sb[4][2];
  if (lane == 0) { sb[wave][0] = s; sb[wave][1] = q; }
  __syncthreads();
  float st = sb[0][0] + sb[1][0] + sb[2][0] + sb[3][0];
  float qt = sb[0][1] + sb[1][1] + sb[2][1] + sb[3][1];
  float mu = st * (1.0f / D_);
  float var = qt * (1.0f / D_) - mu * mu;
  float rstd = rsqrtf(var + 1e-6f);
  const float* mb = mod + (size_t)b * 6144 + goff;
  const int c = t * 4;
  float4 gm = *(const float4*)(mb + c);
  float4 bt = *(const float4*)(mb + 1024 + c);
  bf16x4 pk;
  pk.x = (__bf16)((xv.x - mu) * rstd * (1.0f + bt.x) + gm.x);
  pk.y = (__bf16)((xv.y - mu) * rstd * (1.0f + bt.y) + gm.y);
  pk.z = (__bf16)((xv.z - mu) * rstd * (1.0f + bt.z) + gm.z);
  pk.w = (__bf16)((xv.w - mu) * rstd * (1.0f + bt.w) + gm.w);
  *(bf16x4*)(H + (size_t)row * D_ + c) = pk;
}

// ---------------- V transpose: vT[b,h,d,s] <- qkv[b,s, 2048+h*64+d] ----------------
__global__ __launch_bounds__(256) void transpose_v(
    const bf16_t* __restrict__ qkv, bf16_t* __restrict__ vT) {
  __shared__ bf16_t tile[64][65];
  const int bh = blockIdx.y;
  const int b = bh >> 4, hh = bh & 15;
  const int s0 = blockIdx.x * 64;
  const int t = threadIdx.x;
  const int tx = t & 63, ty = t >> 6;
  const bf16_t* src = qkv + (size_t)b * S_ * 3072 + 2048 + hh * 64;
  for (int r = ty; r < 64; r += 4)
    tile[r][tx] = src[(size_t)(s0 + r) * 3072 + tx];
  __syncthreads();
  bf16_t* dst = vT + (size_t)bh * 64 * 1024;
  for (int r = ty; r < 64; r += 4)
    dst[(size_t)r * 1024 + s0 + tx] = tile[tx][r];
}

// ---------------- flash attention ----------------
// grid (16, 64): x = Q-tile (64 rows), y = b*16+h. 4 waves, each owns 16 Q-rows.
// Per K-tile (128): S = Q K^T /8 (MFMA), online softmax (wave-local rows),
// P -> LDS (C-layout -> A-layout transpose), O += P V (MFMA, V from vT).
__global__ __launch_bounds__(256) void flash_attn(
    const bf16_t* __restrict__ qkv, const bf16_t* __restrict__ vT,
    bf16_t* __restrict__ attn) {
  __shared__ __align__(16) bf16_t Qs[64 * 64];
  __shared__ __align__(16) bf16_t Ks[128 * 64];
  __shared__ __align__(16) bf16_t Vs[64 * 128];
  __shared__ __align__(16) bf16_t Ps[4 * 16 * 136];

  const int t = threadIdx.x;
  const int wave = t >> 6, lane = t & 63;
  const int lm = lane & 15, quad = lane >> 4;
  const int bh = blockIdx.y;
  const int b = bh >> 4, hh = bh & 15;
  const int s0 = blockIdx.x * 64;

  const bf16_t* qbase = qkv + (size_t)b * S_ * 3072 + hh * 64;
  const bf16_t* kbase = qbase + 1024;
  const bf16_t* vbase = vT + (size_t)bh * (64 * 1024);

  // stage Q: 64 rows x 8 chunks (xor-swizzled)
#pragma unroll
  for (int j = 0; j < 2; j++) {
    int slot = j * 256 + t;
    int row = slot >> 3;
    int cg = (slot & 7) ^ (row & 7);
    async_copy16(qbase + (size_t)(s0 + row) * 3072 + cg * 8, &Qs[slot * 8]);
  }

  f32x4 accO[4] = {};
  float mrow[4], lrow[4];
#pragma unroll
  for (int r = 0; r < 4; r++) { mrow[r] = -1e30f; lrow[r] = 0.f; }

  bf16_t* Pw = &Ps[wave * 16 * 136];

  for (int k0 = 0; k0 < S_; k0 += 128) {
    __syncthreads();
    // stage K-tile (128 x 64) and V^T-tile (64 x 128)
#pragma unroll
    for (int j = 0; j < 4; j++) {
      int slot = j * 256 + t;
      int row = slot >> 3;
      int cg = (slot & 7) ^ (row & 7);
      async_copy16(kbase + (size_t)(k0 + row) * 3072 + cg * 8, &Ks[slot * 8]);
    }
#pragma unroll
    for (int j = 0; j < 4; j++) {
      int slot = j * 256 + t;
      int row = slot >> 4;          // d-row 0..63
      int cp = slot & 15;
      int cg = (cp & 8) | ((cp & 7) ^ (row & 7));
      async_copy16(vbase + (size_t)row * 1024 + k0 + cg * 8, &Vs[slot * 8]);
    }
    __syncthreads();

    // S = Q K^T : accS[ni], rows = wave*16 + quad*4 + r, cols = ni*16 + lm
    f32x4 accS[8] = {};
#pragma unroll
    for (int ks = 0; ks < 2; ks++) {
      int rq = wave * 16 + lm;
      int cq = (ks * 4 + quad) ^ (rq & 7);
      bf16x8 aq = *(const bf16x8*)&Qs[rq * 64 + cq * 8];
#pragma unroll
      for (int ni = 0; ni < 8; ni++) {
        int rk = ni * 16 + lm;
        int ck = (ks * 4 + quad) ^ (rk & 7);
        bf16x8 bk8 = *(const bf16x8*)&Ks[rk * 64 + ck * 8];
        accS[ni] = __builtin_amdgcn_mfma_f32_16x16x32_bf16(aq, bk8, accS[ni], 0, 0, 0);
      }
    }

    // online softmax (rows wave-local; reduce over cols = ni frags + lm lanes)
    float alpha[4];
#pragma unroll
    for (int r = 0; r < 4; r++) {
      float mx = accS[0][r];
#pragma unroll
      for (int ni = 1; ni < 8; ni++) mx = fmaxf(mx, accS[ni][r]);
      mx = fmaxf(mx, __shfl_xor(mx, 1));
      mx = fmaxf(mx, __shfl_xor(mx, 2));
      mx = fmaxf(mx, __shfl_xor(mx, 4));
      mx = fmaxf(mx, __shfl_xor(mx, 8));
      mx *= 0.125f;
      float mnew = fmaxf(mrow[r], mx);
      alpha[r] = __expf(mrow[r] - mnew);
      mrow[r] = mnew;
      float sum = 0.f;
#pragma unroll
      for (int ni = 0; ni < 8; ni++) {
        float p = __expf(accS[ni][r] * 0.125f - mnew);
        accS[ni][r] = p;
        sum += p;
      }
      sum += __shfl_xor(sum, 1);
      sum += __shfl_xor(sum, 2);
      sum += __shfl_xor(sum, 4);
      sum += __shfl_xor(sum, 8);
      lrow[r] = lrow[r] * alpha[r] + sum;
    }
#pragma unroll
    for (int di = 0; di < 4; di++)
#pragma unroll
      for (int r = 0; r < 4; r++) accO[di][r] *= alpha[r];

    // P (C-layout) -> wave-private LDS, pitch 136 (conflict-free, 16B-aligned rows)
#pragma unroll
    for (int ni = 0; ni < 8; ni++)
#pragma unroll
      for (int r = 0; r < 4; r++)
        Pw[(quad * 4 + r) * 136 + ni * 16 + lm] = (__bf16)accS[ni][r];

    // O += P V  (A-frag from Pw, B-frag from Vs)
#pragma unroll
    for (int ks2 = 0; ks2 < 4; ks2++) {
      bf16x8 ap = *(const bf16x8*)&Pw[lm * 136 + ks2 * 32 + quad * 8];
#pragma unroll
      for (int di = 0; di < 4; di++) {
        int rv = di * 16 + lm;
        int g = ks2 * 4 + quad;
        int cp = (g & 8) | ((g & 7) ^ (rv & 7));
        bf16x8 bv = *(const bf16x8*)&Vs[rv * 128 + cp * 8];
        accO[di] = __builtin_amdgcn_mfma_f32_16x16x32_bf16(ap, bv, accO[di], 0, 0, 0);
      }
    }
  }

  // epilogue: O/l -> wave-private LDS (pitch 64, chunk-xor) -> coalesced 16B stores
#pragma unroll
  for (int r = 0; r < 4; r++) {
    float inv = 1.0f / lrow[r];
    int row = quad * 4 + r;
#pragma unroll
    for (int di = 0; di < 4; di++) {
      int col = di * 16 + lm;
      int cph = (col >> 3) ^ (row & 7);
      Pw[row * 64 + cph * 8 + (col & 7)] = (__bf16)(accO[di][r] * inv);
    }
  }
  bf16_t* abase = attn + (size_t)b * S_ * 1024 +
                  (size_t)(s0 + wave * 16) * 1024 + hh * 64;
#pragma unroll
  for (int it = 0; it < 2; it++) {
    int slot = it * 64 + lane;
    int row = slot >> 3;
    int cg = slot & 7;
    int cph = cg ^ (row & 7);
    bf16x8 val = *(const bf16x8*)&Pw[row * 64 + cph * 8];
    *(bf16x8*)(abase + (size_t)row * 1024 + cg * 8) = val;
  }
}

// ---------------- generic C = A * B^T GEMM (bf16 in, f32 acc) ----------------
// BK=64, XOR-swizzled LDS.
// EPI: 0 = (+bias) -> bf16 store
//      1 = *scale -> f32 store          (also used for split-K partials)
//      2 = resid + alpha[b,col]*(acc+bias) -> f32 store   (b = row>>10)
//      3 = gelu_erf(acc+bias) -> bf16 store
template <int EPI>
__global__ __launch_bounds__(256) void gemm_bt(
    const bf16_t* __restrict__ A, int lda, long long sAz,
    const bf16_t* __restrict__ B, int ldb, long long sBz,
    void* __restrict__ Cv, int ldc, long long sCz,
    int M, int N, int K,
    const float* __restrict__ bias,
    const float* __restrict__ resid,
    const float* __restrict__ alpha,
    float scale) {
  __shared__ __align__(16) bf16_t As[128 * 64];
  __shared__ __align__(16) bf16_t Bs[128 * 64];

  const int z = blockIdx.z;
  A += (size_t)z * sAz;
  B += (size_t)z * sBz;

  const int t = threadIdx.x;
  const int wave = t >> 6;
  const int lane = t & 63;
  const int lm = lane & 15;
  const int quad = lane >> 4;
  const int wr = wave >> 1;
  const int wc = wave & 1;

  const int m0 = blockIdx.y * 128;
  const int n0 = blockIdx.x * 128;

  f32x4 acc[4][4] = {};

  const int srow = (lane >> 3);
  const int gchunk = (lane & 7) ^ srow;
  const int goff = gchunk * 8;
  const int lds_lin = wave * 2048 + lane * 8;

  for (int k0 = 0; k0 < K; k0 += 64) {
    __syncthreads();
#pragma unroll
    for (int j = 0; j < 4; j++) {
      int row = wave * 32 + j * 8 + srow;
      int ga = m0 + row; if (ga > M - 1) ga = M - 1;
      int gb = n0 + row; if (gb > N - 1) gb = N - 1;
      async_copy16(A + (size_t)ga * lda + k0 + goff, &As[lds_lin + j * 512]);
      async_copy16(B + (size_t)gb * ldb + k0 + goff, &Bs[lds_lin + j * 512]);
    }
    __syncthreads();

#pragma unroll
    for (int ks = 0; ks < 2; ks++) {
      bf16x8 af[4], bfr[4];
#pragma unroll
      for (int i = 0; i < 4; i++) {
        int ra = wr * 64 + i * 16 + lm;
        int ca = (ks * 4 + quad) ^ (ra & 7);
        af[i] = *(const bf16x8*)&As[ra * 64 + ca * 8];
        int rb = wc * 64 + i * 16 + lm;
        int cb = (ks * 4 + quad) ^ (rb & 7);
        bfr[i] = *(const bf16x8*)&Bs[rb * 64 + cb * 8];
      }
#pragma unroll
      for (int mi = 0; mi < 4; mi++)
#pragma unroll
        for (int ni = 0; ni < 4; ni++)
          acc[mi][ni] = __builtin_amdgcn_mfma_f32_16x16x32_bf16(
              af[mi], bfr[ni], acc[mi][ni], 0, 0, 0);
    }
  }

  const size_t cz = (size_t)z * sCz;
#pragma unroll
  for (int mi = 0; mi < 4; mi++) {
#pragma unroll
    for (int ni = 0; ni < 4; ni++) {
#pragma unroll
      for (int r = 0; r < 4; r++) {
        int row = m0 + wr * 64 + mi * 16 + quad * 4 + r;
        int col = n0 + wc * 64 + ni * 16 + lm;
        if (row < M && col < N) {
          float v = acc[mi][ni][r];
          size_t idx = cz + (size_t)row * ldc + col;
          if (EPI == 1) {
            ((float*)Cv)[idx] = v * scale;
          } else if (EPI == 0) {
            if (bias) v += bias[col];
            ((bf16_t*)Cv)[idx] = (__bf16)v;
          } else if (EPI == 3) {
            v += bias[col];
            float g = 0.5f * v * (1.0f + erff(v * 0.70710678118654752f));
            ((bf16_t*)Cv)[idx] = (__bf16)g;
          } else {  // EPI == 2
            v += bias[col];
            int bb = row >> 10;
            float a = alpha[(size_t)bb * 6144 + col];
            ((float*)Cv)[idx] = resid[(size_t)row * ldc + col] + a * v;
          }
        }
      }
    }
  }
}

// ---------------- W2 split-K reduction + epilogue ----------------
// out = x1 + alpha2[b,col] * (sum_z part[z] + b2[col])
__global__ __launch_bounds__(256) void reduce_w2(
    const float* __restrict__ part, const float* __restrict__ x1,
    const float* __restrict__ b2, const float* __restrict__ mod,
    float* __restrict__ out) {
  const int idx = (blockIdx.x * 256 + threadIdx.x) * 4;
  const int col = idx & 1023;
  const int row = idx >> 10;
  const int b = row >> 10;
  float4 s0 = *(const float4*)(part + idx);
  float4 s1 = *(const float4*)(part + 4194304 + idx);
  float4 s2 = *(const float4*)(part + 8388608 + idx);
  float4 s3 = *(const float4*)(part + 12582912 + idx);
  float4 bb = *(const float4*)(b2 + col);
  float4 al = *(const float4*)(mod + (size_t)b * 6144 + 5120 + col);
  float4 rs = *(const float4*)(x1 + idx);
  float4 o;
  o.x = rs.x + al.x * (s0.x + s1.x + s2.x + s3.x + bb.x);
  o.y = rs.y + al.y * (s0.y + s1.y + s2.y + s3.y + bb.y);
  o.z = rs.z + al.z * (s0.z + s1.z + s2.z + s3.z + bb.z);
  o.w = rs.w + al.w * (s0.w + s1.w + s2.w + s3.w + bb.w);
  *(float4*)(out + idx) = o;
}

extern "C" void kernel_launch(void* const* d_in, const int* in_sizes, int n_in,
                              void* d_out, int out_size, void* d_ws, size_t ws_size,
                              hipStream_t stream) {
  (void)in_sizes; (void)n_in; (void)out_size; (void)ws_size;
  const float* x    = (const float*)d_in[0];
  const float* cond = (const float*)d_in[1];
  const float* Wq   = (const float*)d_in[2];
  const float* bq   = (const float*)d_in[3];
  const float* Wk   = (const float*)d_in[4];
  const float* bk   = (const float*)d_in[5];
  const float* Wv   = (const float*)d_in[6];
  const float* bv   = (const float*)d_in[7];
  const float* Wo   = (const float*)d_in[8];
  const float* bo   = (const float*)d_in[9];
  const float* W1   = (const float*)d_in[10];
  const float* b1   = (const float*)d_in[11];
  const float* W2   = (const float*)d_in[12];
  const float* b2   = (const float*)d_in[13];
  const float* Wada = (const float*)d_in[14];
  const float* bada = (const float*)d_in[15];

  uint8_t* ws = (uint8_t*)d_ws;
  bf16_t* wbf   = (bf16_t*)(ws + OFF_WBF);
  float*  bqkv  = (float*)(ws + OFF_BQKV);
  float*  mod   = (float*)(ws + OFF_MOD);
  bf16_t* h     = (bf16_t*)(ws + OFF_H);
  bf16_t* qkv   = (bf16_t*)(ws + OFF_QKV);
  bf16_t* vT    = (bf16_t*)(ws + OFF_VT);
  bf16_t* attn  = (bf16_t*)(ws + OFF_ATTN);
  float*  x1    = (float*)(ws + OFF_X1);
  float*  part  = (float*)(ws + OFF_PART);
  bf16_t* mlph  = (bf16_t*)(ws + OFF_MLPH);
  float* out = (float*)d_out;

  // weights -> bf16, pack qkv bias
  convert_pack<<<dim3(4096, 7, 1), 256, 0, stream>>>(Wq, Wk, Wv, Wo, W1, W2,
                                                     bq, bk, bv, wbf, bqkv);
  // adaLN modulation vector
  ada_mod<<<6144, 256, 0, stream>>>(cond, Wada, bada, mod);
  // h = modulate(ln(x), beta1, gama1)
  ln_modulate<<<4096, 256, 0, stream>>>(x, mod, h, 0);
  // qkv = h @ [Wq;Wk;Wv]^T + bias  (bf16 out)
  gemm_bt<0><<<dim3(24, 32, 1), 256, 0, stream>>>(
      h, 1024, 0, wbf, 1024, 0, qkv, 3072, 0, 4096, 3072, 1024,
      bqkv, nullptr, nullptr, 1.f);
  transpose_v<<<dim3(16, 64, 1), 256, 0, stream>>>(qkv, vT);

  // fused flash attention -> attn
  flash_attn<<<dim3(16, 64, 1), 256, 0, stream>>>(qkv, vT, attn);

  // x1 = x + alpha1 * (attn @ Wo^T + bo)
  gemm_bt<2><<<dim3(8, 32, 1), 256, 0, stream>>>(
      attn, 1024, 0, wbf + (size_t)3 * MEG, 1024, 0, x1, 1024, 0,
      4096, 1024, 1024, bo, x, mod + 2048, 1.f);
  // h = modulate(ln(x1), beta2, gama2)
  ln_modulate<<<4096, 256, 0, stream>>>(x1, mod, h, 3072);
  // mlph = gelu(h @ W1^T + b1)
  gemm_bt<3><<<dim3(32, 32, 1), 256, 0, stream>>>(
      h, 1024, 0, wbf + (size_t)4 * MEG, 1024, 0, mlph, 4096, 0,
      4096, 4096, 1024, b1, nullptr, nullptr, 1.f);
  // W2 split-K=4: part[z] = mlph[:, z*1024:(z+1)*1024] @ W2[:, z*1024:(z+1)*1024]^T
  gemm_bt<1><<<dim3(8, 32, 4), 256, 0, stream>>>(
      mlph, 4096, 1024, wbf + (size_t)8 * MEG, 4096, 1024, part, 1024, 4194304,
      4096, 1024, 1024, nullptr, nullptr, nullptr, 1.f);
  // out = x1 + alpha2 * (sum part + b2)
  reduce_w2<<<4096, 256, 0, stream>>>(part, x1, b2, mod, out);
}

// Round 4
// 462.108 us; speedup vs baseline: 1.5174x; 1.0347x over previous
//
#include <hip/hip_runtime.h>
#include <cstdint>

typedef __bf16 bf16_t;
typedef __bf16 bf16x4 __attribute__((ext_vector_type(4)));
typedef __bf16 bf16x8 __attribute__((ext_vector_type(8)));
typedef float f32x4 __attribute__((ext_vector_type(4)));

#define B_ 4
#define S_ 1024
#define D_ 1024
#define HID_ 4096
#define MEG (1u << 20)

// ---------------- workspace layout (bytes) ----------------
static const size_t OFF_WBF  = 0;                 // 12M bf16 (Wq,Wk,Wv,Wo,W1,W2)
static const size_t OFF_BQKV = 25165824;          // 3072 f32
static const size_t OFF_MOD  = 25178112;          // 4*6144 f32
static const size_t OFF_H    = 25276416;          // 4096*1024 bf16
static const size_t OFF_QKV  = 33665024;          // 4096*3072 bf16
static const size_t OFF_VT   = 58830848;          // 4*16*64*1024 bf16
static const size_t OFF_ATTN = 67219456;          // 4096*1024 bf16
static const size_t OFF_X1   = 75608064;          // 4096*1024 f32
static const size_t OFF_PART = 92385280;          // 4 * 4096*1024 f32 = 64MB (split-K partials)
static const size_t OFF_MLPH = 159494144;         // 4096*4096 bf16 = 32MB

// ---------------- async global->LDS (16B/lane) ----------------
__device__ __forceinline__ void async_copy16(const bf16_t* g, bf16_t* l) {
  __builtin_amdgcn_global_load_lds(
      (__attribute__((address_space(1))) void*)(g),
      (__attribute__((address_space(3))) void*)(l), 16, 0, 0);
}

// ---------------- weight convert + bias pack ----------------
__global__ __launch_bounds__(256) void convert_pack(
    const float* __restrict__ Wq, const float* __restrict__ Wk,
    const float* __restrict__ Wv, const float* __restrict__ Wo,
    const float* __restrict__ W1, const float* __restrict__ W2,
    const float* __restrict__ bq, const float* __restrict__ bk,
    const float* __restrict__ bv, bf16_t* __restrict__ wbf,
    float* __restrict__ bqkv) {
  const int y = blockIdx.y;
  if (y == 6) {
    int i = blockIdx.x * 256 + threadIdx.x;
    if (i < 3072)
      bqkv[i] = i < 1024 ? bq[i] : (i < 2048 ? bk[i - 1024] : bv[i - 2048]);
    return;
  }
  const float* src; bf16_t* dst; int n;
  switch (y) {
    case 0: src = Wq; dst = wbf;           n = MEG;     break;
    case 1: src = Wk; dst = wbf + MEG;     n = MEG;     break;
    case 2: src = Wv; dst = wbf + 2*MEG;   n = MEG;     break;
    case 3: src = Wo; dst = wbf + 3*MEG;   n = MEG;     break;
    case 4: src = W1; dst = wbf + 4*MEG;   n = 4*MEG;   break;
    default: src = W2; dst = wbf + 8*MEG;  n = 4*MEG;   break;
  }
  int idx = (blockIdx.x * 256 + threadIdx.x) * 4;
  if (idx < n) {
    float4 v = *(const float4*)(src + idx);
    bf16x4 pk;
    pk.x = (__bf16)v.x; pk.y = (__bf16)v.y; pk.z = (__bf16)v.z; pk.w = (__bf16)v.w;
    *(bf16x4*)(dst + idx) = pk;
  }
}

// ---------------- adaLN: mod[b,o] = silu(cond[b,:]) . Wada[o,:] + bada[o] ----------------
__global__ __launch_bounds__(256) void ada_mod(
    const float* __restrict__ cond, const float* __restrict__ Wada,
    const float* __restrict__ bada, float* __restrict__ mod) {
  const int wave = threadIdx.x >> 6, lane = threadIdx.x & 63;
  const int gw = blockIdx.x * 4 + wave;     // 0..24575
  const int b = gw / 6144, o = gw % 6144;
  const float* cb = cond + b * D_;
  const float* wr = Wada + (size_t)o * D_;
  float acc = 0.f;
#pragma unroll
  for (int l = 0; l < 16; l++) {
    int i = l * 64 + lane;
    float c = cb[i];
    float s = c / (1.0f + __expf(-c));
    acc += s * wr[i];
  }
#pragma unroll
  for (int offs = 32; offs; offs >>= 1) acc += __shfl_xor(acc, offs);
  if (lane == 0) mod[gw] = acc + bada[o];
}

// ---------------- LayerNorm + modulate -> bf16 ----------------
__global__ __launch_bounds__(256) void ln_modulate(
    const float* __restrict__ X, const float* __restrict__ mod,
    bf16_t* __restrict__ H, int goff) {
  const int row = blockIdx.x;
  const int b = row >> 10;
  const int t = threadIdx.x;
  const float* xr = X + (size_t)row * D_;
  float4 xv = *(const float4*)(xr + t * 4);
  float s = xv.x + xv.y + xv.z + xv.w;
  float q = xv.x*xv.x + xv.y*xv.y + xv.z*xv.z + xv.w*xv.w;
  const int wave = t >> 6, lane = t & 63;
#pragma unroll
  for (int offs = 32; offs; offs >>= 1) {
    s += __shfl_down(s, offs);
    q += __shfl_down(q, offs);
  }
  __shared__ float sb[4][2];
  if (lane == 0) { sb[wave][0] = s; sb[wave][1] = q; }
  __syncthreads();
  float st = sb[0][0] + sb[1][0] + sb[2][0] + sb[3][0];
  float qt = sb[0][1] + sb[1][1] + sb[2][1] + sb[3][1];
  float mu = st * (1.0f / D_);
  float var = qt * (1.0f / D_) - mu * mu;
  float rstd = rsqrtf(var + 1e-6f);
  const float* mb = mod + (size_t)b * 6144 + goff;
  const int c = t * 4;
  float4 gm = *(const float4*)(mb + c);
  float4 bt = *(const float4*)(mb + 1024 + c);
  bf16x4 pk;
  pk.x = (__bf16)((xv.x - mu) * rstd * (1.0f + bt.x) + gm.x);
  pk.y = (__bf16)((xv.y - mu) * rstd * (1.0f + bt.y) + gm.y);
  pk.z = (__bf16)((xv.z - mu) * rstd * (1.0f + bt.z) + gm.z);
  pk.w = (__bf16)((xv.w - mu) * rstd * (1.0f + bt.w) + gm.w);
  *(bf16x4*)(H + (size_t)row * D_ + c) = pk;
}

// ---------------- V transpose: vT[b,h,d,s] <- qkv[b,s, 2048+h*64+d] ----------------
__global__ __launch_bounds__(256) void transpose_v(
    const bf16_t* __restrict__ qkv, bf16_t* __restrict__ vT) {
  __shared__ bf16_t tile[64][65];
  const int bh = blockIdx.y;
  const int b = bh >> 4, hh = bh & 15;
  const int s0 = blockIdx.x * 64;
  const int t = threadIdx.x;
  const int tx = t & 63, ty = t >> 6;
  const bf16_t* src = qkv + (size_t)b * S_ * 3072 + 2048 + hh * 64;
  for (int r = ty; r < 64; r += 4)
    tile[r][tx] = src[(size_t)(s0 + r) * 3072 + tx];
  __syncthreads();
  bf16_t* dst = vT + (size_t)bh * 64 * 1024;
  for (int r = ty; r < 64; r += 4)
    dst[(size_t)r * 1024 + s0 + tx] = tile[tx][r];
}

// ---------------- flash attention ----------------
__global__ __launch_bounds__(256) void flash_attn(
    const bf16_t* __restrict__ qkv, const bf16_t* __restrict__ vT,
    bf16_t* __restrict__ attn) {
  __shared__ __align__(16) bf16_t Qs[64 * 64];
  __shared__ __align__(16) bf16_t Ks[128 * 64];
  __shared__ __align__(16) bf16_t Vs[64 * 128];
  __shared__ __align__(16) bf16_t Ps[4 * 16 * 136];

  const int t = threadIdx.x;
  const int wave = t >> 6, lane = t & 63;
  const int lm = lane & 15, quad = lane >> 4;
  const int bh = blockIdx.y;
  const int b = bh >> 4, hh = bh & 15;
  const int s0 = blockIdx.x * 64;

  const bf16_t* qbase = qkv + (size_t)b * S_ * 3072 + hh * 64;
  const bf16_t* kbase = qbase + 1024;
  const bf16_t* vbase = vT + (size_t)bh * (64 * 1024);

#pragma unroll
  for (int j = 0; j < 2; j++) {
    int slot = j * 256 + t;
    int row = slot >> 3;
    int cg = (slot & 7) ^ (row & 7);
    async_copy16(qbase + (size_t)(s0 + row) * 3072 + cg * 8, &Qs[slot * 8]);
  }

  f32x4 accO[4] = {};
  float mrow[4], lrow[4];
#pragma unroll
  for (int r = 0; r < 4; r++) { mrow[r] = -1e30f; lrow[r] = 0.f; }

  bf16_t* Pw = &Ps[wave * 16 * 136];

  for (int k0 = 0; k0 < S_; k0 += 128) {
    __syncthreads();
#pragma unroll
    for (int j = 0; j < 4; j++) {
      int slot = j * 256 + t;
      int row = slot >> 3;
      int cg = (slot & 7) ^ (row & 7);
      async_copy16(kbase + (size_t)(k0 + row) * 3072 + cg * 8, &Ks[slot * 8]);
    }
#pragma unroll
    for (int j = 0; j < 4; j++) {
      int slot = j * 256 + t;
      int row = slot >> 4;
      int cp = slot & 15;
      int cg = (cp & 8) | ((cp & 7) ^ (row & 7));
      async_copy16(vbase + (size_t)row * 1024 + k0 + cg * 8, &Vs[slot * 8]);
    }
    __syncthreads();

    f32x4 accS[8] = {};
#pragma unroll
    for (int ks = 0; ks < 2; ks++) {
      int rq = wave * 16 + lm;
      int cq = (ks * 4 + quad) ^ (rq & 7);
      bf16x8 aq = *(const bf16x8*)&Qs[rq * 64 + cq * 8];
#pragma unroll
      for (int ni = 0; ni < 8; ni++) {
        int rk = ni * 16 + lm;
        int ck = (ks * 4 + quad) ^ (rk & 7);
        bf16x8 bk8 = *(const bf16x8*)&Ks[rk * 64 + ck * 8];
        accS[ni] = __builtin_amdgcn_mfma_f32_16x16x32_bf16(aq, bk8, accS[ni], 0, 0, 0);
      }
    }

    float alpha[4];
#pragma unroll
    for (int r = 0; r < 4; r++) {
      float mx = accS[0][r];
#pragma unroll
      for (int ni = 1; ni < 8; ni++) mx = fmaxf(mx, accS[ni][r]);
      mx = fmaxf(mx, __shfl_xor(mx, 1));
      mx = fmaxf(mx, __shfl_xor(mx, 2));
      mx = fmaxf(mx, __shfl_xor(mx, 4));
      mx = fmaxf(mx, __shfl_xor(mx, 8));
      mx *= 0.125f;
      float mnew = fmaxf(mrow[r], mx);
      alpha[r] = __expf(mrow[r] - mnew);
      mrow[r] = mnew;
      float sum = 0.f;
#pragma unroll
      for (int ni = 0; ni < 8; ni++) {
        float p = __expf(accS[ni][r] * 0.125f - mnew);
        accS[ni][r] = p;
        sum += p;
      }
      sum += __shfl_xor(sum, 1);
      sum += __shfl_xor(sum, 2);
      sum += __shfl_xor(sum, 4);
      sum += __shfl_xor(sum, 8);
      lrow[r] = lrow[r] * alpha[r] + sum;
    }
#pragma unroll
    for (int di = 0; di < 4; di++)
#pragma unroll
      for (int r = 0; r < 4; r++) accO[di][r] *= alpha[r];

#pragma unroll
    for (int ni = 0; ni < 8; ni++)
#pragma unroll
      for (int r = 0; r < 4; r++)
        Pw[(quad * 4 + r) * 136 + ni * 16 + lm] = (__bf16)accS[ni][r];

#pragma unroll
    for (int ks2 = 0; ks2 < 4; ks2++) {
      bf16x8 ap = *(const bf16x8*)&Pw[lm * 136 + ks2 * 32 + quad * 8];
#pragma unroll
      for (int di = 0; di < 4; di++) {
        int rv = di * 16 + lm;
        int g = ks2 * 4 + quad;
        int cp = (g & 8) | ((g & 7) ^ (rv & 7));
        bf16x8 bv = *(const bf16x8*)&Vs[rv * 128 + cp * 8];
        accO[di] = __builtin_amdgcn_mfma_f32_16x16x32_bf16(ap, bv, accO[di], 0, 0, 0);
      }
    }
  }

#pragma unroll
  for (int r = 0; r < 4; r++) {
    float inv = 1.0f / lrow[r];
    int row = quad * 4 + r;
#pragma unroll
    for (int di = 0; di < 4; di++) {
      int col = di * 16 + lm;
      int cph = (col >> 3) ^ (row & 7);
      Pw[row * 64 + cph * 8 + (col & 7)] = (__bf16)(accO[di][r] * inv);
    }
  }
  bf16_t* abase = attn + (size_t)b * S_ * 1024 +
                  (size_t)(s0 + wave * 16) * 1024 + hh * 64;
#pragma unroll
  for (int it = 0; it < 2; it++) {
    int slot = it * 64 + lane;
    int row = slot >> 3;
    int cg = slot & 7;
    int cph = cg ^ (row & 7);
    bf16x8 val = *(const bf16x8*)&Pw[row * 64 + cph * 8];
    *(bf16x8*)(abase + (size_t)row * 1024 + cg * 8) = val;
  }
}

// ---------------- generic C = A * B^T GEMM (bf16 in, f32 acc) ----------------
// EPI: 0 = (+bias) -> bf16 store
//      1 = *scale -> f32 store (split-K partials)
//      3 = gelu_tanh(acc+bias) -> bf16 store
template <int EPI>
__global__ __launch_bounds__(256) void gemm_bt(
    const bf16_t* __restrict__ A, int lda, long long sAz,
    const bf16_t* __restrict__ B, int ldb, long long sBz,
    void* __restrict__ Cv, int ldc, long long sCz,
    int M, int N, int K,
    const float* __restrict__ bias,
    float scale) {
  __shared__ __align__(16) bf16_t As[128 * 64];
  __shared__ __align__(16) bf16_t Bs[128 * 64];

  const int z = blockIdx.z;
  A += (size_t)z * sAz;
  B += (size_t)z * sBz;

  const int t = threadIdx.x;
  const int wave = t >> 6;
  const int lane = t & 63;
  const int lm = lane & 15;
  const int quad = lane >> 4;
  const int wr = wave >> 1;
  const int wc = wave & 1;

  const int m0 = blockIdx.y * 128;
  const int n0 = blockIdx.x * 128;

  f32x4 acc[4][4] = {};

  const int srow = (lane >> 3);
  const int gchunk = (lane & 7) ^ srow;
  const int goff = gchunk * 8;
  const int lds_lin = wave * 2048 + lane * 8;

  for (int k0 = 0; k0 < K; k0 += 64) {
    __syncthreads();
#pragma unroll
    for (int j = 0; j < 4; j++) {
      int row = wave * 32 + j * 8 + srow;
      int ga = m0 + row; if (ga > M - 1) ga = M - 1;
      int gb = n0 + row; if (gb > N - 1) gb = N - 1;
      async_copy16(A + (size_t)ga * lda + k0 + goff, &As[lds_lin + j * 512]);
      async_copy16(B + (size_t)gb * ldb + k0 + goff, &Bs[lds_lin + j * 512]);
    }
    __syncthreads();

#pragma unroll
    for (int ks = 0; ks < 2; ks++) {
      bf16x8 af[4], bfr[4];
#pragma unroll
      for (int i = 0; i < 4; i++) {
        int ra = wr * 64 + i * 16 + lm;
        int ca = (ks * 4 + quad) ^ (ra & 7);
        af[i] = *(const bf16x8*)&As[ra * 64 + ca * 8];
        int rb = wc * 64 + i * 16 + lm;
        int cb = (ks * 4 + quad) ^ (rb & 7);
        bfr[i] = *(const bf16x8*)&Bs[rb * 64 + cb * 8];
      }
#pragma unroll
      for (int mi = 0; mi < 4; mi++)
#pragma unroll
        for (int ni = 0; ni < 4; ni++)
          acc[mi][ni] = __builtin_amdgcn_mfma_f32_16x16x32_bf16(
              af[mi], bfr[ni], acc[mi][ni], 0, 0, 0);
    }
  }

  const size_t cz = (size_t)z * sCz;
#pragma unroll
  for (int mi = 0; mi < 4; mi++) {
#pragma unroll
    for (int ni = 0; ni < 4; ni++) {
#pragma unroll
      for (int r = 0; r < 4; r++) {
        int row = m0 + wr * 64 + mi * 16 + quad * 4 + r;
        int col = n0 + wc * 64 + ni * 16 + lm;
        if (row < M && col < N) {
          float v = acc[mi][ni][r];
          size_t idx = cz + (size_t)row * ldc + col;
          if (EPI == 1) {
            ((float*)Cv)[idx] = v * scale;
          } else if (EPI == 0) {
            if (bias) v += bias[col];
            ((bf16_t*)Cv)[idx] = (__bf16)v;
          } else if (EPI == 3) {
            v += bias[col];
            // tanh-GELU: v * sigmoid(1.59577*(v + 0.044715 v^3))
            float u = 1.5957691216f * (v + 0.044715f * v * v * v);
            float g = v / (1.0f + __expf(-u));
            ((bf16_t*)Cv)[idx] = (__bf16)g;
          }
        }
      }
    }
  }
}

// ---------------- Wo split-K reduce + residual + LN2 + modulate ----------------
// x1 = x + alpha1*(p0+p1+bo); h = ln(x1)*(1+beta2)+gama2
__global__ __launch_bounds__(256) void reduce_ln(
    const float* __restrict__ part, const float* __restrict__ x,
    const float* __restrict__ bo, const float* __restrict__ mod,
    float* __restrict__ x1, bf16_t* __restrict__ h) {
  const int row = blockIdx.x;
  const int b = row >> 10;
  const int t = threadIdx.x;
  const int c = t * 4;
  const size_t idx = (size_t)row * 1024 + c;
  float4 p0 = *(const float4*)(part + idx);
  float4 p1 = *(const float4*)(part + 4194304 + idx);
  float4 bb = *(const float4*)(bo + c);
  float4 al = *(const float4*)(mod + (size_t)b * 6144 + 2048 + c);
  float4 xs = *(const float4*)(x + idx);
  float4 xv;
  xv.x = xs.x + al.x * (p0.x + p1.x + bb.x);
  xv.y = xs.y + al.y * (p0.y + p1.y + bb.y);
  xv.z = xs.z + al.z * (p0.z + p1.z + bb.z);
  xv.w = xs.w + al.w * (p0.w + p1.w + bb.w);
  *(float4*)(x1 + idx) = xv;

  float s = xv.x + xv.y + xv.z + xv.w;
  float q = xv.x*xv.x + xv.y*xv.y + xv.z*xv.z + xv.w*xv.w;
  const int wave = t >> 6, lane = t & 63;
#pragma unroll
  for (int offs = 32; offs; offs >>= 1) {
    s += __shfl_down(s, offs);
    q += __shfl_down(q, offs);
  }
  __shared__ float sb[4][2];
  if (lane == 0) { sb[wave][0] = s; sb[wave][1] = q; }
  __syncthreads();
  float st = sb[0][0] + sb[1][0] + sb[2][0] + sb[3][0];
  float qt = sb[0][1] + sb[1][1] + sb[2][1] + sb[3][1];
  float mu = st * (1.0f / D_);
  float var = qt * (1.0f / D_) - mu * mu;
  float rstd = rsqrtf(var + 1e-6f);
  const float* mb = mod + (size_t)b * 6144 + 3072;
  float4 gm = *(const float4*)(mb + c);
  float4 bt = *(const float4*)(mb + 1024 + c);
  bf16x4 pk;
  pk.x = (__bf16)((xv.x - mu) * rstd * (1.0f + bt.x) + gm.x);
  pk.y = (__bf16)((xv.y - mu) * rstd * (1.0f + bt.y) + gm.y);
  pk.z = (__bf16)((xv.z - mu) * rstd * (1.0f + bt.z) + gm.z);
  pk.w = (__bf16)((xv.w - mu) * rstd * (1.0f + bt.w) + gm.w);
  *(bf16x4*)(h + idx) = pk;
}

// ---------------- W2 split-K reduction + epilogue ----------------
__global__ __launch_bounds__(256) void reduce_w2(
    const float* __restrict__ part, const float* __restrict__ x1,
    const float* __restrict__ b2, const float* __restrict__ mod,
    float* __restrict__ out) {
  const int idx = (blockIdx.x * 256 + threadIdx.x) * 4;
  const int col = idx & 1023;
  const int row = idx >> 10;
  const int b = row >> 10;
  float4 s0 = *(const float4*)(part + idx);
  float4 s1 = *(const float4*)(part + 4194304 + idx);
  float4 s2 = *(const float4*)(part + 8388608 + idx);
  float4 s3 = *(const float4*)(part + 12582912 + idx);
  float4 bb = *(const float4*)(b2 + col);
  float4 al = *(const float4*)(mod + (size_t)b * 6144 + 5120 + col);
  float4 rs = *(const float4*)(x1 + idx);
  float4 o;
  o.x = rs.x + al.x * (s0.x + s1.x + s2.x + s3.x + bb.x);
  o.y = rs.y + al.y * (s0.y + s1.y + s2.y + s3.y + bb.y);
  o.z = rs.z + al.z * (s0.z + s1.z + s2.z + s3.z + bb.z);
  o.w = rs.w + al.w * (s0.w + s1.w + s2.w + s3.w + bb.w);
  *(float4*)(out + idx) = o;
}

extern "C" void kernel_launch(void* const* d_in, const int* in_sizes, int n_in,
                              void* d_out, int out_size, void* d_ws, size_t ws_size,
                              hipStream_t stream) {
  (void)in_sizes; (void)n_in; (void)out_size; (void)ws_size;
  const float* x    = (const float*)d_in[0];
  const float* cond = (const float*)d_in[1];
  const float* Wq   = (const float*)d_in[2];
  const float* bq   = (const float*)d_in[3];
  const float* Wk   = (const float*)d_in[4];
  const float* bk   = (const float*)d_in[5];
  const float* Wv   = (const float*)d_in[6];
  const float* bv   = (const float*)d_in[7];
  const float* Wo   = (const float*)d_in[8];
  const float* bo   = (const float*)d_in[9];
  const float* W1   = (const float*)d_in[10];
  const float* b1   = (const float*)d_in[11];
  const float* W2   = (const float*)d_in[12];
  const float* b2   = (const float*)d_in[13];
  const float* Wada = (const float*)d_in[14];
  const float* bada = (const float*)d_in[15];

  uint8_t* ws = (uint8_t*)d_ws;
  bf16_t* wbf   = (bf16_t*)(ws + OFF_WBF);
  float*  bqkv  = (float*)(ws + OFF_BQKV);
  float*  mod   = (float*)(ws + OFF_MOD);
  bf16_t* h     = (bf16_t*)(ws + OFF_H);
  bf16_t* qkv   = (bf16_t*)(ws + OFF_QKV);
  bf16_t* vT    = (bf16_t*)(ws + OFF_VT);
  bf16_t* attn  = (bf16_t*)(ws + OFF_ATTN);
  float*  x1    = (float*)(ws + OFF_X1);
  float*  part  = (float*)(ws + OFF_PART);
  bf16_t* mlph  = (bf16_t*)(ws + OFF_MLPH);
  float* out = (float*)d_out;

  convert_pack<<<dim3(4096, 7, 1), 256, 0, stream>>>(Wq, Wk, Wv, Wo, W1, W2,
                                                     bq, bk, bv, wbf, bqkv);
  ada_mod<<<6144, 256, 0, stream>>>(cond, Wada, bada, mod);
  ln_modulate<<<4096, 256, 0, stream>>>(x, mod, h, 0);
  // qkv = h @ [Wq;Wk;Wv]^T + bias
  gemm_bt<0><<<dim3(24, 32, 1), 256, 0, stream>>>(
      h, 1024, 0, wbf, 1024, 0, qkv, 3072, 0, 4096, 3072, 1024,
      bqkv, 1.f);
  transpose_v<<<dim3(16, 64, 1), 256, 0, stream>>>(qkv, vT);
  flash_attn<<<dim3(16, 64, 1), 256, 0, stream>>>(qkv, vT, attn);

  // Wo split-K=2: part[z] = attn[:, z*512:] @ Wo[:, z*512:]^T
  gemm_bt<1><<<dim3(8, 32, 2), 256, 0, stream>>>(
      attn, 1024, 512, wbf + (size_t)3 * MEG, 1024, 512, part, 1024, 4194304,
      4096, 1024, 512, nullptr, 1.f);
  // x1 = x + alpha1*(sum part + bo); h = modulate(ln(x1), beta2, gama2)
  reduce_ln<<<4096, 256, 0, stream>>>(part, x, bo, mod, x1, h);

  // mlph = gelu(h @ W1^T + b1)
  gemm_bt<3><<<dim3(32, 32, 1), 256, 0, stream>>>(
      h, 1024, 0, wbf + (size_t)4 * MEG, 1024, 0, mlph, 4096, 0,
      4096, 4096, 1024, b1, 1.f);
  // W2 split-K=4
  gemm_bt<1><<<dim3(8, 32, 4), 256, 0, stream>>>(
      mlph, 4096, 1024, wbf + (size_t)8 * MEG, 4096, 1024, part, 1024, 4194304,
      4096, 1024, 1024, nullptr, 1.f);
  reduce_w2<<<4096, 256, 0, stream>>>(part, x1, b2, mod, out);
}

// Round 5
// 429.148 us; speedup vs baseline: 1.6339x; 1.0768x over previous
//
#include <hip/hip_runtime.h>
#include <cstdint>

typedef __bf16 bf16_t;
typedef __bf16 bf16x4 __attribute__((ext_vector_type(4)));
typedef __bf16 bf16x8 __attribute__((ext_vector_type(8)));
typedef float f32x4 __attribute__((ext_vector_type(4)));

#define B_ 4
#define S_ 1024
#define D_ 1024
#define HID_ 4096
#define MEG (1u << 20)

// ---------------- workspace layout (bytes) ----------------
static const size_t OFF_WBF  = 0;                 // 12M bf16 (Wq,Wk,Wv,Wo,W1,W2)
static const size_t OFF_BQKV = 25165824;          // 3072 f32
static const size_t OFF_MOD  = 25178112;          // 4*6144 f32
static const size_t OFF_H    = 25276416;          // 4096*1024 bf16
static const size_t OFF_QKV  = 33665024;          // 4096*3072 bf16
static const size_t OFF_VT   = 58830848;          // 4*16*64*1024 bf16
static const size_t OFF_ATTN = 67219456;          // 4096*1024 bf16
static const size_t OFF_X1   = 75608064;          // 4096*1024 f32
static const size_t OFF_PART = 92385280;          // 4 * 4096*1024 f32 = 64MB (split-K partials)
static const size_t OFF_MLPH = 159494144;         // 4096*4096 bf16 = 32MB

// ---------------- async global->LDS (16B/lane) ----------------
__device__ __forceinline__ void async_copy16(const bf16_t* g, bf16_t* l) {
  __builtin_amdgcn_global_load_lds(
      (__attribute__((address_space(1))) void*)(g),
      (__attribute__((address_space(3))) void*)(l), 16, 0, 0);
}

// ---------------- weight convert + bias pack ----------------
__global__ __launch_bounds__(256) void convert_pack(
    const float* __restrict__ Wq, const float* __restrict__ Wk,
    const float* __restrict__ Wv, const float* __restrict__ Wo,
    const float* __restrict__ W1, const float* __restrict__ W2,
    const float* __restrict__ bq, const float* __restrict__ bk,
    const float* __restrict__ bv, bf16_t* __restrict__ wbf,
    float* __restrict__ bqkv) {
  const int y = blockIdx.y;
  if (y == 6) {
    int i = blockIdx.x * 256 + threadIdx.x;
    if (i < 3072)
      bqkv[i] = i < 1024 ? bq[i] : (i < 2048 ? bk[i - 1024] : bv[i - 2048]);
    return;
  }
  const float* src; bf16_t* dst; int n;
  switch (y) {
    case 0: src = Wq; dst = wbf;           n = MEG;     break;
    case 1: src = Wk; dst = wbf + MEG;     n = MEG;     break;
    case 2: src = Wv; dst = wbf + 2*MEG;   n = MEG;     break;
    case 3: src = Wo; dst = wbf + 3*MEG;   n = MEG;     break;
    case 4: src = W1; dst = wbf + 4*MEG;   n = 4*MEG;   break;
    default: src = W2; dst = wbf + 8*MEG;  n = 4*MEG;   break;
  }
  int idx = (blockIdx.x * 256 + threadIdx.x) * 4;
  if (idx < n) {
    float4 v = *(const float4*)(src + idx);
    bf16x4 pk;
    pk.x = (__bf16)v.x; pk.y = (__bf16)v.y; pk.z = (__bf16)v.z; pk.w = (__bf16)v.w;
    *(bf16x4*)(dst + idx) = pk;
  }
}

// ---------------- adaLN: mod[b,o] = silu(cond[b,:]) . Wada[o,:] + bada[o] ----------------
__global__ __launch_bounds__(256) void ada_mod(
    const float* __restrict__ cond, const float* __restrict__ Wada,
    const float* __restrict__ bada, float* __restrict__ mod) {
  const int wave = threadIdx.x >> 6, lane = threadIdx.x & 63;
  const int gw = blockIdx.x * 4 + wave;     // 0..24575
  const int b = gw / 6144, o = gw % 6144;
  const float* cb = cond + b * D_;
  const float* wr = Wada + (size_t)o * D_;
  float acc = 0.f;
#pragma unroll
  for (int l = 0; l < 16; l++) {
    int i = l * 64 + lane;
    float c = cb[i];
    float s = c / (1.0f + __expf(-c));
    acc += s * wr[i];
  }
#pragma unroll
  for (int offs = 32; offs; offs >>= 1) acc += __shfl_xor(acc, offs);
  if (lane == 0) mod[gw] = acc + bada[o];
}

// ---------------- LayerNorm + modulate -> bf16 ----------------
__global__ __launch_bounds__(256) void ln_modulate(
    const float* __restrict__ X, const float* __restrict__ mod,
    bf16_t* __restrict__ H, int goff) {
  const int row = blockIdx.x;
  const int b = row >> 10;
  const int t = threadIdx.x;
  const float* xr = X + (size_t)row * D_;
  float4 xv = *(const float4*)(xr + t * 4);
  float s = xv.x + xv.y + xv.z + xv.w;
  float q = xv.x*xv.x + xv.y*xv.y + xv.z*xv.z + xv.w*xv.w;
  const int wave = t >> 6, lane = t & 63;
#pragma unroll
  for (int offs = 32; offs; offs >>= 1) {
    s += __shfl_down(s, offs);
    q += __shfl_down(q, offs);
  }
  __shared__ float sb[4][2];
  if (lane == 0) { sb[wave][0] = s; sb[wave][1] = q; }
  __syncthreads();
  float st = sb[0][0] + sb[1][0] + sb[2][0] + sb[3][0];
  float qt = sb[0][1] + sb[1][1] + sb[2][1] + sb[3][1];
  float mu = st * (1.0f / D_);
  float var = qt * (1.0f / D_) - mu * mu;
  float rstd = rsqrtf(var + 1e-6f);
  const float* mb = mod + (size_t)b * 6144 + goff;
  const int c = t * 4;
  float4 gm = *(const float4*)(mb + c);
  float4 bt = *(const float4*)(mb + 1024 + c);
  bf16x4 pk;
  pk.x = (__bf16)((xv.x - mu) * rstd * (1.0f + bt.x) + gm.x);
  pk.y = (__bf16)((xv.y - mu) * rstd * (1.0f + bt.y) + gm.y);
  pk.z = (__bf16)((xv.z - mu) * rstd * (1.0f + bt.z) + gm.z);
  pk.w = (__bf16)((xv.w - mu) * rstd * (1.0f + bt.w) + gm.w);
  *(bf16x4*)(H + (size_t)row * D_ + c) = pk;
}

// ---------------- V transpose: vT[b,h,d,s] <- qkv[b,s, 2048+h*64+d] ----------------
__global__ __launch_bounds__(256) void transpose_v(
    const bf16_t* __restrict__ qkv, bf16_t* __restrict__ vT) {
  __shared__ bf16_t tile[64][65];
  const int bh = blockIdx.y;
  const int b = bh >> 4, hh = bh & 15;
  const int s0 = blockIdx.x * 64;
  const int t = threadIdx.x;
  const int tx = t & 63, ty = t >> 6;
  const bf16_t* src = qkv + (size_t)b * S_ * 3072 + 2048 + hh * 64;
  for (int r = ty; r < 64; r += 4)
    tile[r][tx] = src[(size_t)(s0 + r) * 3072 + tx];
  __syncthreads();
  bf16_t* dst = vT + (size_t)bh * 64 * 1024;
  for (int r = ty; r < 64; r += 4)
    dst[(size_t)r * 1024 + s0 + tx] = tile[tx][r];
}

// ---------------- flash attention ----------------
__global__ __launch_bounds__(256) void flash_attn(
    const bf16_t* __restrict__ qkv, const bf16_t* __restrict__ vT,
    bf16_t* __restrict__ attn) {
  __shared__ __align__(16) bf16_t Qs[64 * 64];
  __shared__ __align__(16) bf16_t Ks[128 * 64];
  __shared__ __align__(16) bf16_t Vs[64 * 128];
  __shared__ __align__(16) bf16_t Ps[4 * 16 * 136];

  const int t = threadIdx.x;
  const int wave = t >> 6, lane = t & 63;
  const int lm = lane & 15, quad = lane >> 4;
  const int bh = blockIdx.y;
  const int b = bh >> 4, hh = bh & 15;
  const int s0 = blockIdx.x * 64;

  const bf16_t* qbase = qkv + (size_t)b * S_ * 3072 + hh * 64;
  const bf16_t* kbase = qbase + 1024;
  const bf16_t* vbase = vT + (size_t)bh * (64 * 1024);

#pragma unroll
  for (int j = 0; j < 2; j++) {
    int slot = j * 256 + t;
    int row = slot >> 3;
    int cg = (slot & 7) ^ (row & 7);
    async_copy16(qbase + (size_t)(s0 + row) * 3072 + cg * 8, &Qs[slot * 8]);
  }

  f32x4 accO[4] = {};
  float mrow[4], lrow[4];
#pragma unroll
  for (int r = 0; r < 4; r++) { mrow[r] = -1e30f; lrow[r] = 0.f; }

  bf16_t* Pw = &Ps[wave * 16 * 136];

  for (int k0 = 0; k0 < S_; k0 += 128) {
    __syncthreads();
#pragma unroll
    for (int j = 0; j < 4; j++) {
      int slot = j * 256 + t;
      int row = slot >> 3;
      int cg = (slot & 7) ^ (row & 7);
      async_copy16(kbase + (size_t)(k0 + row) * 3072 + cg * 8, &Ks[slot * 8]);
    }
#pragma unroll
    for (int j = 0; j < 4; j++) {
      int slot = j * 256 + t;
      int row = slot >> 4;
      int cp = slot & 15;
      int cg = (cp & 8) | ((cp & 7) ^ (row & 7));
      async_copy16(vbase + (size_t)row * 1024 + k0 + cg * 8, &Vs[slot * 8]);
    }
    __syncthreads();

    f32x4 accS[8] = {};
#pragma unroll
    for (int ks = 0; ks < 2; ks++) {
      int rq = wave * 16 + lm;
      int cq = (ks * 4 + quad) ^ (rq & 7);
      bf16x8 aq = *(const bf16x8*)&Qs[rq * 64 + cq * 8];
#pragma unroll
      for (int ni = 0; ni < 8; ni++) {
        int rk = ni * 16 + lm;
        int ck = (ks * 4 + quad) ^ (rk & 7);
        bf16x8 bk8 = *(const bf16x8*)&Ks[rk * 64 + ck * 8];
        accS[ni] = __builtin_amdgcn_mfma_f32_16x16x32_bf16(aq, bk8, accS[ni], 0, 0, 0);
      }
    }

    float alpha[4];
#pragma unroll
    for (int r = 0; r < 4; r++) {
      float mx = accS[0][r];
#pragma unroll
      for (int ni = 1; ni < 8; ni++) mx = fmaxf(mx, accS[ni][r]);
      mx = fmaxf(mx, __shfl_xor(mx, 1));
      mx = fmaxf(mx, __shfl_xor(mx, 2));
      mx = fmaxf(mx, __shfl_xor(mx, 4));
      mx = fmaxf(mx, __shfl_xor(mx, 8));
      mx *= 0.125f;
      float mnew = fmaxf(mrow[r], mx);
      alpha[r] = __expf(mrow[r] - mnew);
      mrow[r] = mnew;
      float sum = 0.f;
#pragma unroll
      for (int ni = 0; ni < 8; ni++) {
        float p = __expf(accS[ni][r] * 0.125f - mnew);
        accS[ni][r] = p;
        sum += p;
      }
      sum += __shfl_xor(sum, 1);
      sum += __shfl_xor(sum, 2);
      sum += __shfl_xor(sum, 4);
      sum += __shfl_xor(sum, 8);
      lrow[r] = lrow[r] * alpha[r] + sum;
    }
#pragma unroll
    for (int di = 0; di < 4; di++)
#pragma unroll
      for (int r = 0; r < 4; r++) accO[di][r] *= alpha[r];

#pragma unroll
    for (int ni = 0; ni < 8; ni++)
#pragma unroll
      for (int r = 0; r < 4; r++)
        Pw[(quad * 4 + r) * 136 + ni * 16 + lm] = (__bf16)accS[ni][r];

#pragma unroll
    for (int ks2 = 0; ks2 < 4; ks2++) {
      bf16x8 ap = *(const bf16x8*)&Pw[lm * 136 + ks2 * 32 + quad * 8];
#pragma unroll
      for (int di = 0; di < 4; di++) {
        int rv = di * 16 + lm;
        int g = ks2 * 4 + quad;
        int cp = (g & 8) | ((g & 7) ^ (rv & 7));
        bf16x8 bv = *(const bf16x8*)&Vs[rv * 128 + cp * 8];
        accO[di] = __builtin_amdgcn_mfma_f32_16x16x32_bf16(ap, bv, accO[di], 0, 0, 0);
      }
    }
  }

#pragma unroll
  for (int r = 0; r < 4; r++) {
    float inv = 1.0f / lrow[r];
    int row = quad * 4 + r;
#pragma unroll
    for (int di = 0; di < 4; di++) {
      int col = di * 16 + lm;
      int cph = (col >> 3) ^ (row & 7);
      Pw[row * 64 + cph * 8 + (col & 7)] = (__bf16)(accO[di][r] * inv);
    }
  }
  bf16_t* abase = attn + (size_t)b * S_ * 1024 +
                  (size_t)(s0 + wave * 16) * 1024 + hh * 64;
#pragma unroll
  for (int it = 0; it < 2; it++) {
    int slot = it * 64 + lane;
    int row = slot >> 3;
    int cg = slot & 7;
    int cph = cg ^ (row & 7);
    bf16x8 val = *(const bf16x8*)&Pw[row * 64 + cph * 8];
    *(bf16x8*)(abase + (size_t)row * 1024 + cg * 8) = val;
  }
}

// ---------------- generic C = A * B^T GEMM, pipelined double-buffer ----------------
// BK=32, 2 LDS buffers, ONE barrier per K-iter; next tile's global_load_lds
// issued right after the barrier so the whole compute body overlaps them.
// M,N must be multiples of 128; K multiple of 32.
// EPI: 0 = (+bias) -> bf16 store
//      1 = *scale -> f32 store (split-K partials)
//      3 = gelu_tanh(acc+bias) -> bf16 store
template <int EPI>
__global__ __launch_bounds__(256) void gemm_bt(
    const bf16_t* __restrict__ A, int lda, long long sAz,
    const bf16_t* __restrict__ B, int ldb, long long sBz,
    void* __restrict__ Cv, int ldc, long long sCz,
    int M, int N, int K,
    const float* __restrict__ bias,
    float scale) {
  __shared__ __align__(16) bf16_t As[2][128 * 32];
  __shared__ __align__(16) bf16_t Bs[2][128 * 32];

  const int z = blockIdx.z;
  A += (size_t)z * sAz;
  B += (size_t)z * sBz;

  const int t = threadIdx.x;
  const int wave = t >> 6;
  const int lane = t & 63;
  const int lm = lane & 15;
  const int quad = lane >> 4;
  const int wr = wave >> 1;
  const int wc = wave & 1;

  const int m0 = blockIdx.y * 128;
  const int n0 = blockIdx.x * 128;

  f32x4 acc[4][4] = {};

  // staging: thread t covers rows {t>>2, 64+(t>>2)}, chunk slot t&3 (xor-swizzled)
  const int srow = t >> 2;                 // 0..63
  const int gch = (t & 3) ^ (srow & 3);    // global chunk 0..3
  const int lds_off = t * 8;               // lane-linear (required by global_load_lds)
  const bf16_t* Ap0 = A + (size_t)(m0 + srow) * lda + gch * 8;
  const bf16_t* Ap1 = A + (size_t)(m0 + 64 + srow) * lda + gch * 8;
  const bf16_t* Bp0 = B + (size_t)(n0 + srow) * ldb + gch * 8;
  const bf16_t* Bp1 = B + (size_t)(n0 + 64 + srow) * ldb + gch * 8;

  const int niter = K >> 5;
  // prologue: tile 0 -> buffer 0
  async_copy16(Ap0, &As[0][lds_off]);
  async_copy16(Ap1, &As[0][2048 + lds_off]);
  async_copy16(Bp0, &Bs[0][lds_off]);
  async_copy16(Bp1, &Bs[0][2048 + lds_off]);

  for (int it = 0; it < niter; ++it) {
    // own tile-it loads drained, then barrier => tile it fully in LDS for all
    // waves; buffer (it+1)&1 free (its readers all passed the previous barrier).
    asm volatile("s_waitcnt vmcnt(0)\n\ts_barrier" ::: "memory");
    if (it + 1 < niter) {
      const int ko = (it + 1) << 5;
      const int nb = (it + 1) & 1;
      async_copy16(Ap0 + ko, &As[nb][lds_off]);
      async_copy16(Ap1 + ko, &As[nb][2048 + lds_off]);
      async_copy16(Bp0 + ko, &Bs[nb][lds_off]);
      async_copy16(Bp1 + ko, &Bs[nb][2048 + lds_off]);
    }
    const int cb = it & 1;
    bf16x8 af[4], bfr[4];
#pragma unroll
    for (int i = 0; i < 4; i++) {
      int ra = wr * 64 + i * 16 + lm;
      af[i] = *(const bf16x8*)&As[cb][ra * 32 + ((quad ^ (ra & 3)) * 8)];
      int rb = wc * 64 + i * 16 + lm;
      bfr[i] = *(const bf16x8*)&Bs[cb][rb * 32 + ((quad ^ (rb & 3)) * 8)];
    }
#pragma unroll
    for (int mi = 0; mi < 4; mi++)
#pragma unroll
      for (int ni = 0; ni < 4; ni++)
        acc[mi][ni] = __builtin_amdgcn_mfma_f32_16x16x32_bf16(
            af[mi], bfr[ni], acc[mi][ni], 0, 0, 0);
  }

  const size_t cz = (size_t)z * sCz;
#pragma unroll
  for (int mi = 0; mi < 4; mi++) {
#pragma unroll
    for (int ni = 0; ni < 4; ni++) {
#pragma unroll
      for (int r = 0; r < 4; r++) {
        int row = m0 + wr * 64 + mi * 16 + quad * 4 + r;
        int col = n0 + wc * 64 + ni * 16 + lm;
        float v = acc[mi][ni][r];
        size_t idx = cz + (size_t)row * ldc + col;
        if (EPI == 1) {
          ((float*)Cv)[idx] = v * scale;
        } else if (EPI == 0) {
          if (bias) v += bias[col];
          ((bf16_t*)Cv)[idx] = (__bf16)v;
        } else if (EPI == 3) {
          v += bias[col];
          // tanh-GELU: v * sigmoid(1.59577*(v + 0.044715 v^3))
          float u = 1.5957691216f * (v + 0.044715f * v * v * v);
          float g = v / (1.0f + __expf(-u));
          ((bf16_t*)Cv)[idx] = (__bf16)g;
        }
      }
    }
  }
}

// ---------------- Wo split-K reduce + residual + LN2 + modulate ----------------
__global__ __launch_bounds__(256) void reduce_ln(
    const float* __restrict__ part, const float* __restrict__ x,
    const float* __restrict__ bo, const float* __restrict__ mod,
    float* __restrict__ x1, bf16_t* __restrict__ h) {
  const int row = blockIdx.x;
  const int b = row >> 10;
  const int t = threadIdx.x;
  const int c = t * 4;
  const size_t idx = (size_t)row * 1024 + c;
  float4 p0 = *(const float4*)(part + idx);
  float4 p1 = *(const float4*)(part + 4194304 + idx);
  float4 bb = *(const float4*)(bo + c);
  float4 al = *(const float4*)(mod + (size_t)b * 6144 + 2048 + c);
  float4 xs = *(const float4*)(x + idx);
  float4 xv;
  xv.x = xs.x + al.x * (p0.x + p1.x + bb.x);
  xv.y = xs.y + al.y * (p0.y + p1.y + bb.y);
  xv.z = xs.z + al.z * (p0.z + p1.z + bb.z);
  xv.w = xs.w + al.w * (p0.w + p1.w + bb.w);
  *(float4*)(x1 + idx) = xv;

  float s = xv.x + xv.y + xv.z + xv.w;
  float q = xv.x*xv.x + xv.y*xv.y + xv.z*xv.z + xv.w*xv.w;
  const int wave = t >> 6, lane = t & 63;
#pragma unroll
  for (int offs = 32; offs; offs >>= 1) {
    s += __shfl_down(s, offs);
    q += __shfl_down(q, offs);
  }
  __shared__ float sb[4][2];
  if (lane == 0) { sb[wave][0] = s; sb[wave][1] = q; }
  __syncthreads();
  float st = sb[0][0] + sb[1][0] + sb[2][0] + sb[3][0];
  float qt = sb[0][1] + sb[1][1] + sb[2][1] + sb[3][1];
  float mu = st * (1.0f / D_);
  float var = qt * (1.0f / D_) - mu * mu;
  float rstd = rsqrtf(var + 1e-6f);
  const float* mb = mod + (size_t)b * 6144 + 3072;
  float4 gm = *(const float4*)(mb + c);
  float4 bt = *(const float4*)(mb + 1024 + c);
  bf16x4 pk;
  pk.x = (__bf16)((xv.x - mu) * rstd * (1.0f + bt.x) + gm.x);
  pk.y = (__bf16)((xv.y - mu) * rstd * (1.0f + bt.y) + gm.y);
  pk.z = (__bf16)((xv.z - mu) * rstd * (1.0f + bt.z) + gm.z);
  pk.w = (__bf16)((xv.w - mu) * rstd * (1.0f + bt.w) + gm.w);
  *(bf16x4*)(h + idx) = pk;
}

// ---------------- W2 split-K reduction + epilogue ----------------
__global__ __launch_bounds__(256) void reduce_w2(
    const float* __restrict__ part, const float* __restrict__ x1,
    const float* __restrict__ b2, const float* __restrict__ mod,
    float* __restrict__ out) {
  const int idx = (blockIdx.x * 256 + threadIdx.x) * 4;
  const int col = idx & 1023;
  const int row = idx >> 10;
  const int b = row >> 10;
  float4 s0 = *(const float4*)(part + idx);
  float4 s1 = *(const float4*)(part + 4194304 + idx);
  float4 s2 = *(const float4*)(part + 8388608 + idx);
  float4 s3 = *(const float4*)(part + 12582912 + idx);
  float4 bb = *(const float4*)(b2 + col);
  float4 al = *(const float4*)(mod + (size_t)b * 6144 + 5120 + col);
  float4 rs = *(const float4*)(x1 + idx);
  float4 o;
  o.x = rs.x + al.x * (s0.x + s1.x + s2.x + s3.x + bb.x);
  o.y = rs.y + al.y * (s0.y + s1.y + s2.y + s3.y + bb.y);
  o.z = rs.z + al.z * (s0.z + s1.z + s2.z + s3.z + bb.z);
  o.w = rs.w + al.w * (s0.w + s1.w + s2.w + s3.w + bb.w);
  *(float4*)(out + idx) = o;
}

extern "C" void kernel_launch(void* const* d_in, const int* in_sizes, int n_in,
                              void* d_out, int out_size, void* d_ws, size_t ws_size,
                              hipStream_t stream) {
  (void)in_sizes; (void)n_in; (void)out_size; (void)ws_size;
  const float* x    = (const float*)d_in[0];
  const float* cond = (const float*)d_in[1];
  const float* Wq   = (const float*)d_in[2];
  const float* bq   = (const float*)d_in[3];
  const float* Wk   = (const float*)d_in[4];
  const float* bk   = (const float*)d_in[5];
  const float* Wv   = (const float*)d_in[6];
  const float* bv   = (const float*)d_in[7];
  const float* Wo   = (const float*)d_in[8];
  const float* bo   = (const float*)d_in[9];
  const float* W1   = (const float*)d_in[10];
  const float* b1   = (const float*)d_in[11];
  const float* W2   = (const float*)d_in[12];
  const float* b2   = (const float*)d_in[13];
  const float* Wada = (const float*)d_in[14];
  const float* bada = (const float*)d_in[15];

  uint8_t* ws = (uint8_t*)d_ws;
  bf16_t* wbf   = (bf16_t*)(ws + OFF_WBF);
  float*  bqkv  = (float*)(ws + OFF_BQKV);
  float*  mod   = (float*)(ws + OFF_MOD);
  bf16_t* h     = (bf16_t*)(ws + OFF_H);
  bf16_t* qkv   = (bf16_t*)(ws + OFF_QKV);
  bf16_t* vT    = (bf16_t*)(ws + OFF_VT);
  bf16_t* attn  = (bf16_t*)(ws + OFF_ATTN);
  float*  x1    = (float*)(ws + OFF_X1);
  float*  part  = (float*)(ws + OFF_PART);
  bf16_t* mlph  = (bf16_t*)(ws + OFF_MLPH);
  float* out = (float*)d_out;

  convert_pack<<<dim3(4096, 7, 1), 256, 0, stream>>>(Wq, Wk, Wv, Wo, W1, W2,
                                                     bq, bk, bv, wbf, bqkv);
  ada_mod<<<6144, 256, 0, stream>>>(cond, Wada, bada, mod);
  ln_modulate<<<4096, 256, 0, stream>>>(x, mod, h, 0);
  // qkv = h @ [Wq;Wk;Wv]^T + bias
  gemm_bt<0><<<dim3(24, 32, 1), 256, 0, stream>>>(
      h, 1024, 0, wbf, 1024, 0, qkv, 3072, 0, 4096, 3072, 1024,
      bqkv, 1.f);
  transpose_v<<<dim3(16, 64, 1), 256, 0, stream>>>(qkv, vT);
  flash_attn<<<dim3(16, 64, 1), 256, 0, stream>>>(qkv, vT, attn);

  // Wo split-K=2: part[z] = attn[:, z*512:] @ Wo[:, z*512:]^T
  gemm_bt<1><<<dim3(8, 32, 2), 256, 0, stream>>>(
      attn, 1024, 512, wbf + (size_t)3 * MEG, 1024, 512, part, 1024, 4194304,
      4096, 1024, 512, nullptr, 1.f);
  // x1 = x + alpha1*(sum part + bo); h = modulate(ln(x1), beta2, gama2)
  reduce_ln<<<4096, 256, 0, stream>>>(part, x, bo, mod, x1, h);

  // mlph = gelu(h @ W1^T + b1)
  gemm_bt<3><<<dim3(32, 32, 1), 256, 0, stream>>>(
      h, 1024, 0, wbf + (size_t)4 * MEG, 1024, 0, mlph, 4096, 0,
      4096, 4096, 1024, b1, 1.f);
  // W2 split-K=4
  gemm_bt<1><<<dim3(8, 32, 4), 256, 0, stream>>>(
      mlph, 4096, 1024, wbf + (size_t)8 * MEG, 4096, 1024, part, 1024, 4194304,
      4096, 1024, 1024, nullptr, 1.f);
  reduce_w2<<<4096, 256, 0, stream>>>(part, x1, b2, mod, out);
}

// Round 6
// 401.240 us; speedup vs baseline: 1.7476x; 1.0696x over previous
//
#include <hip/hip_runtime.h>
#include <cstdint>

typedef __bf16 bf16_t;
typedef __bf16 bf16x4 __attribute__((ext_vector_type(4)));
typedef __bf16 bf16x8 __attribute__((ext_vector_type(8)));
typedef float f32x4 __attribute__((ext_vector_type(4)));

#define B_ 4
#define S_ 1024
#define D_ 1024
#define HID_ 4096
#define MEG (1u << 20)

// ---------------- workspace layout (bytes) ----------------
static const size_t OFF_WBF  = 0;                 // 12M bf16 (Wq,Wk,Wv,Wo,W1,W2)
static const size_t OFF_BQKV = 25165824;          // 3072 f32
static const size_t OFF_MOD  = 25178112;          // 4*6144 f32
static const size_t OFF_H    = 25276416;          // 4096*1024 bf16
static const size_t OFF_QKV  = 33665024;          // 4096*3072 bf16
static const size_t OFF_VT   = 58830848;          // 4*16*64*1024 bf16
static const size_t OFF_ATTN = 67219456;          // 4096*1024 bf16
static const size_t OFF_X1   = 75608064;          // 4096*1024 f32
static const size_t OFF_PART = 92385280;          // 2 * 4096*1024 f32 (split-K partials)
static const size_t OFF_MLPH = 159494144;         // 4096*4096 bf16 = 32MB

// ---------------- async global->LDS (16B/lane) ----------------
__device__ __forceinline__ void async_copy16(const bf16_t* g, bf16_t* l) {
  __builtin_amdgcn_global_load_lds(
      (__attribute__((address_space(1))) void*)(g),
      (__attribute__((address_space(3))) void*)(l), 16, 0, 0);
}

// ---------------- weight convert + bias pack ----------------
__global__ __launch_bounds__(256) void convert_pack(
    const float* __restrict__ Wq, const float* __restrict__ Wk,
    const float* __restrict__ Wv, const float* __restrict__ Wo,
    const float* __restrict__ W1, const float* __restrict__ W2,
    const float* __restrict__ bq, const float* __restrict__ bk,
    const float* __restrict__ bv, bf16_t* __restrict__ wbf,
    float* __restrict__ bqkv) {
  const int y = blockIdx.y;
  if (y == 6) {
    int i = blockIdx.x * 256 + threadIdx.x;
    if (i < 3072)
      bqkv[i] = i < 1024 ? bq[i] : (i < 2048 ? bk[i - 1024] : bv[i - 2048]);
    return;
  }
  const float* src; bf16_t* dst; int n;
  switch (y) {
    case 0: src = Wq; dst = wbf;           n = MEG;     break;
    case 1: src = Wk; dst = wbf + MEG;     n = MEG;     break;
    case 2: src = Wv; dst = wbf + 2*MEG;   n = MEG;     break;
    case 3: src = Wo; dst = wbf + 3*MEG;   n = MEG;     break;
    case 4: src = W1; dst = wbf + 4*MEG;   n = 4*MEG;   break;
    default: src = W2; dst = wbf + 8*MEG;  n = 4*MEG;   break;
  }
  int idx = (blockIdx.x * 256 + threadIdx.x) * 4;
  if (idx < n) {
    float4 v = *(const float4*)(src + idx);
    bf16x4 pk;
    pk.x = (__bf16)v.x; pk.y = (__bf16)v.y; pk.z = (__bf16)v.z; pk.w = (__bf16)v.w;
    *(bf16x4*)(dst + idx) = pk;
  }
}

// ---------------- adaLN: one wave per output o, all 4 batches ----------------
__global__ __launch_bounds__(256) void ada_mod(
    const float* __restrict__ cond, const float* __restrict__ Wada,
    const float* __restrict__ bada, float* __restrict__ mod) {
  const int wave = threadIdx.x >> 6, lane = threadIdx.x & 63;
  const int o = blockIdx.x * 4 + wave;      // 0..6143
  const float* wr = Wada + (size_t)o * D_;
  float a0 = 0.f, a1 = 0.f, a2 = 0.f, a3 = 0.f;
#pragma unroll
  for (int l = 0; l < 16; l++) {
    int i = l * 64 + lane;
    float w = wr[i];
    float c0 = cond[i], c1 = cond[1024 + i], c2 = cond[2048 + i], c3 = cond[3072 + i];
    a0 += w * (c0 / (1.0f + __expf(-c0)));
    a1 += w * (c1 / (1.0f + __expf(-c1)));
    a2 += w * (c2 / (1.0f + __expf(-c2)));
    a3 += w * (c3 / (1.0f + __expf(-c3)));
  }
#pragma unroll
  for (int offs = 32; offs; offs >>= 1) {
    a0 += __shfl_xor(a0, offs);
    a1 += __shfl_xor(a1, offs);
    a2 += __shfl_xor(a2, offs);
    a3 += __shfl_xor(a3, offs);
  }
  if (lane == 0) {
    float bb = bada[o];
    mod[o]          = a0 + bb;
    mod[6144 + o]   = a1 + bb;
    mod[12288 + o]  = a2 + bb;
    mod[18432 + o]  = a3 + bb;
  }
}

// ---------------- LayerNorm + modulate -> bf16 ----------------
__global__ __launch_bounds__(256) void ln_modulate(
    const float* __restrict__ X, const float* __restrict__ mod,
    bf16_t* __restrict__ H, int goff) {
  const int row = blockIdx.x;
  const int b = row >> 10;
  const int t = threadIdx.x;
  const float* xr = X + (size_t)row * D_;
  float4 xv = *(const float4*)(xr + t * 4);
  float s = xv.x + xv.y + xv.z + xv.w;
  float q = xv.x*xv.x + xv.y*xv.y + xv.z*xv.z + xv.w*xv.w;
  const int wave = t >> 6, lane = t & 63;
#pragma unroll
  for (int offs = 32; offs; offs >>= 1) {
    s += __shfl_down(s, offs);
    q += __shfl_down(q, offs);
  }
  __shared__ float sb[4][2];
  if (lane == 0) { sb[wave][0] = s; sb[wave][1] = q; }
  __syncthreads();
  float st = sb[0][0] + sb[1][0] + sb[2][0] + sb[3][0];
  float qt = sb[0][1] + sb[1][1] + sb[2][1] + sb[3][1];
  float mu = st * (1.0f / D_);
  float var = qt * (1.0f / D_) - mu * mu;
  float rstd = rsqrtf(var + 1e-6f);
  const float* mb = mod + (size_t)b * 6144 + goff;
  const int c = t * 4;
  float4 gm = *(const float4*)(mb + c);
  float4 bt = *(const float4*)(mb + 1024 + c);
  bf16x4 pk;
  pk.x = (__bf16)((xv.x - mu) * rstd * (1.0f + bt.x) + gm.x);
  pk.y = (__bf16)((xv.y - mu) * rstd * (1.0f + bt.y) + gm.y);
  pk.z = (__bf16)((xv.z - mu) * rstd * (1.0f + bt.z) + gm.z);
  pk.w = (__bf16)((xv.w - mu) * rstd * (1.0f + bt.w) + gm.w);
  *(bf16x4*)(H + (size_t)row * D_ + c) = pk;
}

// ---------------- V transpose: vT[b,h,d,s] <- qkv[b,s, 2048+h*64+d] ----------------
__global__ __launch_bounds__(256) void transpose_v(
    const bf16_t* __restrict__ qkv, bf16_t* __restrict__ vT) {
  __shared__ bf16_t tile[64][65];
  const int bh = blockIdx.y;
  const int b = bh >> 4, hh = bh & 15;
  const int s0 = blockIdx.x * 64;
  const int t = threadIdx.x;
  const int tx = t & 63, ty = t >> 6;
  const bf16_t* src = qkv + (size_t)b * S_ * 3072 + 2048 + hh * 64;
  for (int r = ty; r < 64; r += 4)
    tile[r][tx] = src[(size_t)(s0 + r) * 3072 + tx];
  __syncthreads();
  bf16_t* dst = vT + (size_t)bh * 64 * 1024;
  for (int r = ty; r < 64; r += 4)
    dst[(size_t)r * 1024 + s0 + tx] = tile[tx][r];
}

// ---------------- flash attention ----------------
__global__ __launch_bounds__(256) void flash_attn(
    const bf16_t* __restrict__ qkv, const bf16_t* __restrict__ vT,
    bf16_t* __restrict__ attn) {
  __shared__ __align__(16) bf16_t Qs[64 * 64];
  __shared__ __align__(16) bf16_t Ks[128 * 64];
  __shared__ __align__(16) bf16_t Vs[64 * 128];
  __shared__ __align__(16) bf16_t Ps[4 * 16 * 136];

  const int t = threadIdx.x;
  const int wave = t >> 6, lane = t & 63;
  const int lm = lane & 15, quad = lane >> 4;
  const int bh = blockIdx.y;
  const int b = bh >> 4, hh = bh & 15;
  const int s0 = blockIdx.x * 64;

  const bf16_t* qbase = qkv + (size_t)b * S_ * 3072 + hh * 64;
  const bf16_t* kbase = qbase + 1024;
  const bf16_t* vbase = vT + (size_t)bh * (64 * 1024);

#pragma unroll
  for (int j = 0; j < 2; j++) {
    int slot = j * 256 + t;
    int row = slot >> 3;
    int cg = (slot & 7) ^ (row & 7);
    async_copy16(qbase + (size_t)(s0 + row) * 3072 + cg * 8, &Qs[slot * 8]);
  }

  f32x4 accO[4] = {};
  float mrow[4], lrow[4];
#pragma unroll
  for (int r = 0; r < 4; r++) { mrow[r] = -1e30f; lrow[r] = 0.f; }

  bf16_t* Pw = &Ps[wave * 16 * 136];

  for (int k0 = 0; k0 < S_; k0 += 128) {
    __syncthreads();
#pragma unroll
    for (int j = 0; j < 4; j++) {
      int slot = j * 256 + t;
      int row = slot >> 3;
      int cg = (slot & 7) ^ (row & 7);
      async_copy16(kbase + (size_t)(k0 + row) * 3072 + cg * 8, &Ks[slot * 8]);
    }
#pragma unroll
    for (int j = 0; j < 4; j++) {
      int slot = j * 256 + t;
      int row = slot >> 4;
      int cp = slot & 15;
      int cg = (cp & 8) | ((cp & 7) ^ (row & 7));
      async_copy16(vbase + (size_t)row * 1024 + k0 + cg * 8, &Vs[slot * 8]);
    }
    __syncthreads();

    f32x4 accS[8] = {};
#pragma unroll
    for (int ks = 0; ks < 2; ks++) {
      int rq = wave * 16 + lm;
      int cq = (ks * 4 + quad) ^ (rq & 7);
      bf16x8 aq = *(const bf16x8*)&Qs[rq * 64 + cq * 8];
#pragma unroll
      for (int ni = 0; ni < 8; ni++) {
        int rk = ni * 16 + lm;
        int ck = (ks * 4 + quad) ^ (rk & 7);
        bf16x8 bk8 = *(const bf16x8*)&Ks[rk * 64 + ck * 8];
        accS[ni] = __builtin_amdgcn_mfma_f32_16x16x32_bf16(aq, bk8, accS[ni], 0, 0, 0);
      }
    }

    float alpha[4];
#pragma unroll
    for (int r = 0; r < 4; r++) {
      float mx = accS[0][r];
#pragma unroll
      for (int ni = 1; ni < 8; ni++) mx = fmaxf(mx, accS[ni][r]);
      mx = fmaxf(mx, __shfl_xor(mx, 1));
      mx = fmaxf(mx, __shfl_xor(mx, 2));
      mx = fmaxf(mx, __shfl_xor(mx, 4));
      mx = fmaxf(mx, __shfl_xor(mx, 8));
      mx *= 0.125f;
      float mnew = fmaxf(mrow[r], mx);
      alpha[r] = __expf(mrow[r] - mnew);
      mrow[r] = mnew;
      float sum = 0.f;
#pragma unroll
      for (int ni = 0; ni < 8; ni++) {
        float p = __expf(accS[ni][r] * 0.125f - mnew);
        accS[ni][r] = p;
        sum += p;
      }
      sum += __shfl_xor(sum, 1);
      sum += __shfl_xor(sum, 2);
      sum += __shfl_xor(sum, 4);
      sum += __shfl_xor(sum, 8);
      lrow[r] = lrow[r] * alpha[r] + sum;
    }
#pragma unroll
    for (int di = 0; di < 4; di++)
#pragma unroll
      for (int r = 0; r < 4; r++) accO[di][r] *= alpha[r];

#pragma unroll
    for (int ni = 0; ni < 8; ni++)
#pragma unroll
      for (int r = 0; r < 4; r++)
        Pw[(quad * 4 + r) * 136 + ni * 16 + lm] = (__bf16)accS[ni][r];

#pragma unroll
    for (int ks2 = 0; ks2 < 4; ks2++) {
      bf16x8 ap = *(const bf16x8*)&Pw[lm * 136 + ks2 * 32 + quad * 8];
#pragma unroll
      for (int di = 0; di < 4; di++) {
        int rv = di * 16 + lm;
        int g = ks2 * 4 + quad;
        int cp = (g & 8) | ((g & 7) ^ (rv & 7));
        bf16x8 bv = *(const bf16x8*)&Vs[rv * 128 + cp * 8];
        accO[di] = __builtin_amdgcn_mfma_f32_16x16x32_bf16(ap, bv, accO[di], 0, 0, 0);
      }
    }
  }

#pragma unroll
  for (int r = 0; r < 4; r++) {
    float inv = 1.0f / lrow[r];
    int row = quad * 4 + r;
#pragma unroll
    for (int di = 0; di < 4; di++) {
      int col = di * 16 + lm;
      int cph = (col >> 3) ^ (row & 7);
      Pw[row * 64 + cph * 8 + (col & 7)] = (__bf16)(accO[di][r] * inv);
    }
  }
  bf16_t* abase = attn + (size_t)b * S_ * 1024 +
                  (size_t)(s0 + wave * 16) * 1024 + hh * 64;
#pragma unroll
  for (int it = 0; it < 2; it++) {
    int slot = it * 64 + lane;
    int row = slot >> 3;
    int cg = slot & 7;
    int cph = cg ^ (row & 7);
    bf16x8 val = *(const bf16x8*)&Pw[row * 64 + cph * 8];
    *(bf16x8*)(abase + (size_t)row * 1024 + cg * 8) = val;
  }
}

// ---------------- generic C = A * B^T GEMM, pipelined double-buffer ----------------
// BK=32, 2 LDS buffers, one barrier per K-iter, loads issued after the barrier.
// LDS slot swizzle: slot s of row r holds global chunk s ^ ((r>>1)&3)
// (reader granule = 4*(lm&1) + quad^((lm>>1)&3): all 8 granules x2 -> conflict-free).
// XCD-aware block swizzle (requires gridDim.y == 32): per-XCD 8x4 patches.
// M,N multiples of 128; K multiple of 32.
// EPI: 0 = (+bias) -> bf16 ; 1 = *scale -> f32 ; 3 = gelu_tanh(acc+bias) -> bf16
template <int EPI>
__global__ __launch_bounds__(256) void gemm_bt(
    const bf16_t* __restrict__ A, int lda, long long sAz,
    const bf16_t* __restrict__ B, int ldb, long long sBz,
    void* __restrict__ Cv, int ldc, long long sCz,
    int M, int N, int K,
    const float* __restrict__ bias,
    float scale) {
  __shared__ __align__(16) bf16_t As[2][128 * 32];
  __shared__ __align__(16) bf16_t Bs[2][128 * 32];

  const int z = blockIdx.z;
  A += (size_t)z * sAz;
  B += (size_t)z * sBz;

  // XCD-aware swizzle: dispatch id d -> XCD d&7; give each XCD an 8x4 tile patch
  {
    int d = blockIdx.x + gridDim.x * blockIdx.y;
    int xcd = d & 7, sId = d >> 3;
    int qq = sId & 31, panel = sId >> 5;
    const int bx = panel * 8 + (qq >> 2);
    const int by = xcd * 4 + (qq & 3);
    // fallthrough uses m0/n0 below
    const int t = threadIdx.x;
    const int wave = t >> 6;
    const int lane = t & 63;
    const int lm = lane & 15;
    const int quad = lane >> 4;
    const int wr = wave >> 1;
    const int wc = wave & 1;

    const int m0 = by * 128;
    const int n0 = bx * 128;

    f32x4 acc[4][4] = {};

    // staging: thread t covers rows {t>>2, 64+(t>>2)}, LDS slot t&3 holds
    // global chunk (t&3) ^ ((srow>>1)&3)  [same for srow and srow+64]
    const int srow = t >> 2;
    const int gch = (t & 3) ^ ((srow >> 1) & 3);
    const int lds_off = t * 8;
    const bf16_t* Ap0 = A + (size_t)(m0 + srow) * lda + gch * 8;
    const bf16_t* Ap1 = A + (size_t)(m0 + 64 + srow) * lda + gch * 8;
    const bf16_t* Bp0 = B + (size_t)(n0 + srow) * ldb + gch * 8;
    const bf16_t* Bp1 = B + (size_t)(n0 + 64 + srow) * ldb + gch * 8;

    // reader slot offset: loop-invariant ((ra>>1)&3 == (lm>>1)&3)
    const int sOff = (quad ^ ((lm >> 1) & 3)) * 8;

    const int niter = K >> 5;
    async_copy16(Ap0, &As[0][lds_off]);
    async_copy16(Ap1, &As[0][2048 + lds_off]);
    async_copy16(Bp0, &Bs[0][lds_off]);
    async_copy16(Bp1, &Bs[0][2048 + lds_off]);

    for (int it = 0; it < niter; ++it) {
      asm volatile("s_waitcnt vmcnt(0)\n\ts_barrier" ::: "memory");
      if (it + 1 < niter) {
        const int ko = (it + 1) << 5;
        const int nb = (it + 1) & 1;
        async_copy16(Ap0 + ko, &As[nb][lds_off]);
        async_copy16(Ap1 + ko, &As[nb][2048 + lds_off]);
        async_copy16(Bp0 + ko, &Bs[nb][lds_off]);
        async_copy16(Bp1 + ko, &Bs[nb][2048 + lds_off]);
      }
      const int cb = it & 1;
      bf16x8 af[4], bfr[4];
#pragma unroll
      for (int i = 0; i < 4; i++) {
        af[i] = *(const bf16x8*)&As[cb][(wr * 64 + i * 16 + lm) * 32 + sOff];
        bfr[i] = *(const bf16x8*)&Bs[cb][(wc * 64 + i * 16 + lm) * 32 + sOff];
      }
#pragma unroll
      for (int mi = 0; mi < 4; mi++)
#pragma unroll
        for (int ni = 0; ni < 4; ni++)
          acc[mi][ni] = __builtin_amdgcn_mfma_f32_16x16x32_bf16(
              af[mi], bfr[ni], acc[mi][ni], 0, 0, 0);
    }

    const size_t cz = (size_t)z * sCz;
#pragma unroll
    for (int mi = 0; mi < 4; mi++) {
#pragma unroll
      for (int ni = 0; ni < 4; ni++) {
#pragma unroll
        for (int r = 0; r < 4; r++) {
          int row = m0 + wr * 64 + mi * 16 + quad * 4 + r;
          int col = n0 + wc * 64 + ni * 16 + lm;
          float v = acc[mi][ni][r];
          size_t idx = cz + (size_t)row * ldc + col;
          if (EPI == 1) {
            ((float*)Cv)[idx] = v * scale;
          } else if (EPI == 0) {
            if (bias) v += bias[col];
            ((bf16_t*)Cv)[idx] = (__bf16)v;
          } else if (EPI == 3) {
            v += bias[col];
            float u = 1.5957691216f * (v + 0.044715f * v * v * v);
            float g = v / (1.0f + __expf(-u));
            ((bf16_t*)Cv)[idx] = (__bf16)g;
          }
        }
      }
    }
  }
}

// ---------------- Wo split-K reduce + residual + LN2 + modulate ----------------
__global__ __launch_bounds__(256) void reduce_ln(
    const float* __restrict__ part, const float* __restrict__ x,
    const float* __restrict__ bo, const float* __restrict__ mod,
    float* __restrict__ x1, bf16_t* __restrict__ h) {
  const int row = blockIdx.x;
  const int b = row >> 10;
  const int t = threadIdx.x;
  const int c = t * 4;
  const size_t idx = (size_t)row * 1024 + c;
  float4 p0 = *(const float4*)(part + idx);
  float4 p1 = *(const float4*)(part + 4194304 + idx);
  float4 bb = *(const float4*)(bo + c);
  float4 al = *(const float4*)(mod + (size_t)b * 6144 + 2048 + c);
  float4 xs = *(const float4*)(x + idx);
  float4 xv;
  xv.x = xs.x + al.x * (p0.x + p1.x + bb.x);
  xv.y = xs.y + al.y * (p0.y + p1.y + bb.y);
  xv.z = xs.z + al.z * (p0.z + p1.z + bb.z);
  xv.w = xs.w + al.w * (p0.w + p1.w + bb.w);
  *(float4*)(x1 + idx) = xv;

  float s = xv.x + xv.y + xv.z + xv.w;
  float q = xv.x*xv.x + xv.y*xv.y + xv.z*xv.z + xv.w*xv.w;
  const int wave = t >> 6, lane = t & 63;
#pragma unroll
  for (int offs = 32; offs; offs >>= 1) {
    s += __shfl_down(s, offs);
    q += __shfl_down(q, offs);
  }
  __shared__ float sb[4][2];
  if (lane == 0) { sb[wave][0] = s; sb[wave][1] = q; }
  __syncthreads();
  float st = sb[0][0] + sb[1][0] + sb[2][0] + sb[3][0];
  float qt = sb[0][1] + sb[1][1] + sb[2][1] + sb[3][1];
  float mu = st * (1.0f / D_);
  float var = qt * (1.0f / D_) - mu * mu;
  float rstd = rsqrtf(var + 1e-6f);
  const float* mb = mod + (size_t)b * 6144 + 3072;
  float4 gm = *(const float4*)(mb + c);
  float4 bt = *(const float4*)(mb + 1024 + c);
  bf16x4 pk;
  pk.x = (__bf16)((xv.x - mu) * rstd * (1.0f + bt.x) + gm.x);
  pk.y = (__bf16)((xv.y - mu) * rstd * (1.0f + bt.y) + gm.y);
  pk.z = (__bf16)((xv.z - mu) * rstd * (1.0f + bt.z) + gm.z);
  pk.w = (__bf16)((xv.w - mu) * rstd * (1.0f + bt.w) + gm.w);
  *(bf16x4*)(h + idx) = pk;
}

// ---------------- W2 split-K(2) reduction + epilogue ----------------
__global__ __launch_bounds__(256) void reduce_w2(
    const float* __restrict__ part, const float* __restrict__ x1,
    const float* __restrict__ b2, const float* __restrict__ mod,
    float* __restrict__ out) {
  const int idx = (blockIdx.x * 256 + threadIdx.x) * 4;
  const int col = idx & 1023;
  const int row = idx >> 10;
  const int b = row >> 10;
  float4 s0 = *(const float4*)(part + idx);
  float4 s1 = *(const float4*)(part + 4194304 + idx);
  float4 bb = *(const float4*)(b2 + col);
  float4 al = *(const float4*)(mod + (size_t)b * 6144 + 5120 + col);
  float4 rs = *(const float4*)(x1 + idx);
  float4 o;
  o.x = rs.x + al.x * (s0.x + s1.x + bb.x);
  o.y = rs.y + al.y * (s0.y + s1.y + bb.y);
  o.z = rs.z + al.z * (s0.z + s1.z + bb.z);
  o.w = rs.w + al.w * (s0.w + s1.w + bb.w);
  *(float4*)(out + idx) = o;
}

extern "C" void kernel_launch(void* const* d_in, const int* in_sizes, int n_in,
                              void* d_out, int out_size, void* d_ws, size_t ws_size,
                              hipStream_t stream) {
  (void)in_sizes; (void)n_in; (void)out_size; (void)ws_size;
  const float* x    = (const float*)d_in[0];
  const float* cond = (const float*)d_in[1];
  const float* Wq   = (const float*)d_in[2];
  const float* bq   = (const float*)d_in[3];
  const float* Wk   = (const float*)d_in[4];
  const float* bk   = (const float*)d_in[5];
  const float* Wv   = (const float*)d_in[6];
  const float* bv   = (const float*)d_in[7];
  const float* Wo   = (const float*)d_in[8];
  const float* bo   = (const float*)d_in[9];
  const float* W1   = (const float*)d_in[10];
  const float* b1   = (const float*)d_in[11];
  const float* W2   = (const float*)d_in[12];
  const float* b2   = (const float*)d_in[13];
  const float* Wada = (const float*)d_in[14];
  const float* bada = (const float*)d_in[15];

  uint8_t* ws = (uint8_t*)d_ws;
  bf16_t* wbf   = (bf16_t*)(ws + OFF_WBF);
  float*  bqkv  = (float*)(ws + OFF_BQKV);
  float*  mod   = (float*)(ws + OFF_MOD);
  bf16_t* h     = (bf16_t*)(ws + OFF_H);
  bf16_t* qkv   = (bf16_t*)(ws + OFF_QKV);
  bf16_t* vT    = (bf16_t*)(ws + OFF_VT);
  bf16_t* attn  = (bf16_t*)(ws + OFF_ATTN);
  float*  x1    = (float*)(ws + OFF_X1);
  float*  part  = (float*)(ws + OFF_PART);
  bf16_t* mlph  = (bf16_t*)(ws + OFF_MLPH);
  float* out = (float*)d_out;

  convert_pack<<<dim3(4096, 7, 1), 256, 0, stream>>>(Wq, Wk, Wv, Wo, W1, W2,
                                                     bq, bk, bv, wbf, bqkv);
  ada_mod<<<1536, 256, 0, stream>>>(cond, Wada, bada, mod);
  ln_modulate<<<4096, 256, 0, stream>>>(x, mod, h, 0);
  // qkv = h @ [Wq;Wk;Wv]^T + bias
  gemm_bt<0><<<dim3(24, 32, 1), 256, 0, stream>>>(
      h, 1024, 0, wbf, 1024, 0, qkv, 3072, 0, 4096, 3072, 1024,
      bqkv, 1.f);
  transpose_v<<<dim3(16, 64, 1), 256, 0, stream>>>(qkv, vT);
  flash_attn<<<dim3(16, 64, 1), 256, 0, stream>>>(qkv, vT, attn);

  // Wo split-K=2: part[z] = attn[:, z*512:] @ Wo[:, z*512:]^T
  gemm_bt<1><<<dim3(8, 32, 2), 256, 0, stream>>>(
      attn, 1024, 512, wbf + (size_t)3 * MEG, 1024, 512, part, 1024, 4194304,
      4096, 1024, 512, nullptr, 1.f);
  // x1 = x + alpha1*(sum part + bo); h = modulate(ln(x1), beta2, gama2)
  reduce_ln<<<4096, 256, 0, stream>>>(part, x, bo, mod, x1, h);

  // mlph = gelu(h @ W1^T + b1)
  gemm_bt<3><<<dim3(32, 32, 1), 256, 0, stream>>>(
      h, 1024, 0, wbf + (size_t)4 * MEG, 1024, 0, mlph, 4096, 0,
      4096, 4096, 1024, b1, 1.f);
  // W2 split-K=2
  gemm_bt<1><<<dim3(8, 32, 2), 256, 0, stream>>>(
      mlph, 4096, 2048, wbf + (size_t)8 * MEG, 4096, 2048, part, 1024, 4194304,
      4096, 1024, 2048, nullptr, 1.f);
  reduce_w2<<<4096, 256, 0, stream>>>(part, x1, b2, mod, out);
}